// Round 1
// 428.812 us; speedup vs baseline: 1.0608x; 1.0608x over previous
//
#include <hip/hip_runtime.h>

#define D 128
#define FILLV 0.5f
#define PAD 16   // counters strided to 64B lines
#define NXCD 8

typedef unsigned short u16;
typedef unsigned long long u64;

__device__ __forceinline__ u16 f2bf(float f) {          // RNE fp32 -> bf16
    unsigned u = __float_as_uint(f);
    u += 0x7FFF + ((u >> 16) & 1);
    return (u16)(u >> 16);
}
__device__ __forceinline__ float bf2f(u16 h) {
    return __uint_as_float(((unsigned)h) << 16);
}

// ---------------------------------------------------------------------------
// Convert both feature matrices to bf16 staging copies (RNE).
__global__ void tobf_kernel(const float* __restrict__ x_s, const float* __restrict__ x_t,
                            u16* __restrict__ xb_s, u16* __restrict__ xb_t, long long nd) {
    long long t = (long long)blockIdx.x * blockDim.x + threadIdx.x;
    long long q = nd / 4;
    const float* x; u16* xb; long long i;
    if (t < q) { x = x_s; xb = xb_s; i = t * 4; }
    else if (t < 2 * q) { x = x_t; xb = xb_t; i = (t - q) * 4; }
    else return;
    float4 v = *(const float4*)(x + i);
    ushort4 o;
    o.x = f2bf(v.x); o.y = f2bf(v.y); o.z = f2bf(v.z); o.w = f2bf(v.w);
    *(ushort4*)(xb + i) = o;
}

// Pass 1: ONE packed 64-bit atomic per edge-direction:
//   high word += 1 (count), low word += w * 2^24 (fixed-point degree).
// Max degree ~60 << 256, so the fixed sum (< 2^24*256 = 2^32) never carries
// into the count word. Line j<N keyed by col, line N+r keyed by row.
// NEW: the atomic RETURN's high word is this edge's within-bucket rank.
// Save both ranks packed u16x2 (coalesced, nontemporal) -> fill needs no atomics.
__global__ void cnt_deg_kernel(const int* __restrict__ row, const int* __restrict__ col,
                               const float* __restrict__ w,
                               u64* __restrict__ cntp64, unsigned* __restrict__ ranks,
                               int E, int N) {
    int e = blockIdx.x * blockDim.x + threadIdx.x;
    if (e >= E) return;
    int r = row[e], c = col[e];
    unsigned fx = (unsigned)(w[e] * 16777216.0f);       // w * 2^24
    u64 add = (1ull << 32) | fx;
    u64 oc = atomicAdd(&cntp64[(size_t)c * (PAD / 2)], add);        // s-side bucket (col)
    u64 orr = atomicAdd(&cntp64[(size_t)(N + r) * (PAD / 2)], add); // t-side bucket (N+row)
    unsigned pk = ((unsigned)(orr >> 32) << 16) | ((unsigned)(oc >> 32) & 0xffffu);
    __builtin_nontemporal_store(pk, ranks + e);
}

// Unpack: dinv[i] = 1/(deg+FILL); re-store plain count for the scan phases.
__global__ void invert_kernel(int* __restrict__ cntp, float* __restrict__ dinv, int total) {
    int i = blockIdx.x * blockDim.x + threadIdx.x;
    if (i >= total) return;
    u64 v = *(const u64*)&cntp[(size_t)i * PAD];
    float deg = (float)(unsigned)(v & 0xffffffffu) * (1.0f / 16777216.0f);
    dinv[i] = 1.0f / (deg + FILLV);
    cntp[(size_t)i * PAD] = (int)(v >> 32);
}

// --------------------------- 3-phase parallel scan --------------------------
__global__ void scanA_kernel(const int* __restrict__ cntp, int* __restrict__ tsum, int total) {
    __shared__ int sh[256];
    int gid = blockIdx.x * 256 + threadIdx.x;
    sh[threadIdx.x] = (gid < total) ? cntp[(size_t)gid * PAD] : 0;
    __syncthreads();
    for (int off = 128; off > 0; off >>= 1) {
        if (threadIdx.x < off) sh[threadIdx.x] += sh[threadIdx.x + off];
        __syncthreads();
    }
    if (threadIdx.x == 0) tsum[blockIdx.x] = sh[0];
}

__global__ void scanB_kernel(const int* __restrict__ tsum, int* __restrict__ toff, int nt) {
    __shared__ int sh[512];
    int t = threadIdx.x;
    int v = (t < nt) ? tsum[t] : 0;
    sh[t] = v;
    __syncthreads();
    for (int off = 1; off < 512; off <<= 1) {
        int u = 0;
        if (t >= off) u = sh[t - off];
        __syncthreads();
        sh[t] += u;
        __syncthreads();
    }
    if (t < nt) toff[t] = sh[t] - v;
}

__global__ void scanC_kernel(const int* __restrict__ cntp, const int* __restrict__ toff,
                             int* __restrict__ start, int total, int grand_total) {
    __shared__ int sh[256];
    int gid = blockIdx.x * 256 + threadIdx.x;
    int v = (gid < total) ? cntp[(size_t)gid * PAD] : 0;
    sh[threadIdx.x] = v;
    __syncthreads();
    for (int off = 1; off < 256; off <<= 1) {
        int u = 0;
        if (threadIdx.x >= off) u = sh[threadIdx.x - off];
        __syncthreads();
        sh[threadIdx.x] += u;
        __syncthreads();
    }
    int run = toff[blockIdx.x] + sh[threadIdx.x] - v;   // exclusive
    if (gid < total) start[gid] = run;
    if (gid == 0) start[total] = grand_total;
}

// Pass 2 (replaces atomic fill): XCD-range-partitioned deterministic scatter.
// Slot space [0, 2E) split into NXCD contiguous 64B-aligned ranges; blocks with
// blockIdx&7 == r land on XCD r (round-robin dispatch) and write ONLY slots in
// range r -> the ~8 payloads sharing a 64B line all merge in ONE XCD's L2 and
// write back as full lines (kills the 8x write amplification). Edge stream is
// read 8x redundantly but sequentially (nontemporal so it doesn't evict the
// 1.6MB write window from L2); slot = start[bucket] + saved rank, no atomics.
__global__ void fillR_kernel(const int* __restrict__ start,
                             const int* __restrict__ row, const int* __restrict__ col,
                             const float* __restrict__ w, const unsigned* __restrict__ ranks,
                             const float* __restrict__ dinv,
                             int2* __restrict__ edges, int E, int N, int SL) {
    int e = (int)(blockIdx.x >> 3) * blockDim.x + threadIdx.x;
    int rid = blockIdx.x & 7;
    if (e >= E) return;
    int lo = rid * SL, hi = lo + SL;
    int r = __builtin_nontemporal_load(row + e);
    int c = __builtin_nontemporal_load(col + e);
    float we = __builtin_nontemporal_load(w + e);
    unsigned pk = __builtin_nontemporal_load(ranks + e);
    int ss = start[c] + (int)(pk & 0xffffu);        // s-side slot (bucket col)
    int st = start[N + r] + (int)(pk >> 16);        // t-side slot (bucket N+row)
    bool ds = (ss >= lo) & (ss < hi);
    bool dt = (st >= lo) & (st < hi);
    if (ds) {
        float wns = we * dinv[N + r];               // s-side: normalize by deg_s (row key)
        edges[ss] = make_int2(r, __float_as_int(wns));
    }
    if (dt) {
        float wnt = we * dinv[c];                   // t-side: normalize by deg_t (col key)
        edges[st] = make_int2(c, __float_as_int(wnt));
    }
}

// ---------------------------------------------------------------------------
// Pull kernels: wave per bucket; HALF-WAVE per edge (bf16 row = 256B = 32
// lanes x ushort4). Main loop: 8 edges/iter (4 per half, 4 gathers in flight);
// mid step 4; tail by half 0. Payload loads are wave-uniform -> s_load.
__global__ void pull1_kernel(const int* __restrict__ start, const int2* __restrict__ edges,
                             const float* __restrict__ dinv,
                             const u16* __restrict__ xb_s, const u16* __restrict__ xb_t,
                             const float* __restrict__ x_s, const float* __restrict__ x_t,
                             u16* __restrict__ ab_s, u16* __restrict__ ab_t, int N) {
    int wid0 = (int)(((long long)blockIdx.x * blockDim.x + threadIdx.x) >> 6);
    int wid = __builtin_amdgcn_readfirstlane(wid0);
    int lane = threadIdx.x & 63;
    int half = lane >> 5, hl = lane & 31;
    if (wid >= 2 * N) return;
    const u16* xb; const float* x; u16* ab; int i, o;
    if (wid < N) { i = wid;     o = N; xb = xb_s; x = x_s; ab = ab_s; }
    else         { i = wid - N; o = 0; xb = xb_t; x = x_t; ab = ab_t; }
    int s0 = start[wid], s1 = start[wid + 1];
    float a0 = 0.f, a1 = 0.f, a2 = 0.f, a3 = 0.f;
    int k = s0;
    for (; k + 8 <= s1; k += 8) {
        int b = k + 4 * half;
        int2 p0 = edges[b], p1 = edges[b + 1], p2 = edges[b + 2], p3 = edges[b + 3];
        ushort4 v0 = *(const ushort4*)(xb + (size_t)p0.x * D + hl * 4);
        ushort4 v1 = *(const ushort4*)(xb + (size_t)p1.x * D + hl * 4);
        ushort4 v2 = *(const ushort4*)(xb + (size_t)p2.x * D + hl * 4);
        ushort4 v3 = *(const ushort4*)(xb + (size_t)p3.x * D + hl * 4);
        float w0v = __int_as_float(p0.y), w1v = __int_as_float(p1.y);
        float w2v = __int_as_float(p2.y), w3v = __int_as_float(p3.y);
        a0 += w0v * bf2f(v0.x) + w1v * bf2f(v1.x) + w2v * bf2f(v2.x) + w3v * bf2f(v3.x);
        a1 += w0v * bf2f(v0.y) + w1v * bf2f(v1.y) + w2v * bf2f(v2.y) + w3v * bf2f(v3.y);
        a2 += w0v * bf2f(v0.z) + w1v * bf2f(v1.z) + w2v * bf2f(v2.z) + w3v * bf2f(v3.z);
        a3 += w0v * bf2f(v0.w) + w1v * bf2f(v1.w) + w2v * bf2f(v2.w) + w3v * bf2f(v3.w);
    }
    if (k + 4 <= s1) {
        int b = k + 2 * half;
        int2 p0 = edges[b], p1 = edges[b + 1];
        ushort4 v0 = *(const ushort4*)(xb + (size_t)p0.x * D + hl * 4);
        ushort4 v1 = *(const ushort4*)(xb + (size_t)p1.x * D + hl * 4);
        float w0v = __int_as_float(p0.y), w1v = __int_as_float(p1.y);
        a0 += w0v * bf2f(v0.x) + w1v * bf2f(v1.x);
        a1 += w0v * bf2f(v0.y) + w1v * bf2f(v1.y);
        a2 += w0v * bf2f(v0.z) + w1v * bf2f(v1.z);
        a3 += w0v * bf2f(v0.w) + w1v * bf2f(v1.w);
        k += 4;
    }
    for (; k < s1; ++k) {
        if (half == 0) {
            int2 p = edges[k];
            ushort4 v = *(const ushort4*)(xb + (size_t)p.x * D + hl * 4);
            float wv = __int_as_float(p.y);
            a0 += wv * bf2f(v.x); a1 += wv * bf2f(v.y);
            a2 += wv * bf2f(v.z); a3 += wv * bf2f(v.w);
        }
    }
    a0 += __shfl_xor(a0, 32); a1 += __shfl_xor(a1, 32);
    a2 += __shfl_xor(a2, 32); a3 += __shfl_xor(a3, 32);
    if (half == 0) {
        float sw = FILLV * dinv[o + i];
        float4 xv = *(const float4*)(x + (size_t)i * D + hl * 4);
        a0 += sw * xv.x; a1 += sw * xv.y; a2 += sw * xv.z; a3 += sw * xv.w;
        ushort4 ov;
        ov.x = f2bf(a0); ov.y = f2bf(a1); ov.z = f2bf(a2); ov.w = f2bf(a3);
        *(ushort4*)(ab + (size_t)i * D + hl * 4) = ov;
    }
}

// Hop-2 pull + fused epilogue: out_half = w0*x + w1*a + w2*(conv(a)).
__global__ void pull2_kernel(const int* __restrict__ start, const int2* __restrict__ edges,
                             const float* __restrict__ dinv,
                             const u16* __restrict__ ab_s, const u16* __restrict__ ab_t,
                             const float* __restrict__ x_s, const float* __restrict__ x_t,
                             float* __restrict__ out,
                             const float* __restrict__ w_s, const float* __restrict__ w_t, int N) {
    int wid0 = (int)(((long long)blockIdx.x * blockDim.x + threadIdx.x) >> 6);
    int wid = __builtin_amdgcn_readfirstlane(wid0);
    int lane = threadIdx.x & 63;
    int half = lane >> 5, hl = lane & 31;
    if (wid >= 2 * N) return;
    const u16* ab; const float* x; const float* wv3; int i, o, hoff;
    if (wid < N) { i = wid;     o = N; ab = ab_s; x = x_s; wv3 = w_s; hoff = 0; }
    else         { i = wid - N; o = 0; ab = ab_t; x = x_t; wv3 = w_t; hoff = D; }
    int s0 = start[wid], s1 = start[wid + 1];
    float a0 = 0.f, a1 = 0.f, a2 = 0.f, a3 = 0.f;
    int k = s0;
    for (; k + 8 <= s1; k += 8) {
        int b = k + 4 * half;
        int2 p0 = edges[b], p1 = edges[b + 1], p2 = edges[b + 2], p3 = edges[b + 3];
        ushort4 v0 = *(const ushort4*)(ab + (size_t)p0.x * D + hl * 4);
        ushort4 v1 = *(const ushort4*)(ab + (size_t)p1.x * D + hl * 4);
        ushort4 v2 = *(const ushort4*)(ab + (size_t)p2.x * D + hl * 4);
        ushort4 v3 = *(const ushort4*)(ab + (size_t)p3.x * D + hl * 4);
        float w0v = __int_as_float(p0.y), w1v = __int_as_float(p1.y);
        float w2v = __int_as_float(p2.y), w3v = __int_as_float(p3.y);
        a0 += w0v * bf2f(v0.x) + w1v * bf2f(v1.x) + w2v * bf2f(v2.x) + w3v * bf2f(v3.x);
        a1 += w0v * bf2f(v0.y) + w1v * bf2f(v1.y) + w2v * bf2f(v2.y) + w3v * bf2f(v3.y);
        a2 += w0v * bf2f(v0.z) + w1v * bf2f(v1.z) + w2v * bf2f(v2.z) + w3v * bf2f(v3.z);
        a3 += w0v * bf2f(v0.w) + w1v * bf2f(v1.w) + w2v * bf2f(v2.w) + w3v * bf2f(v3.w);
    }
    if (k + 4 <= s1) {
        int b = k + 2 * half;
        int2 p0 = edges[b], p1 = edges[b + 1];
        ushort4 v0 = *(const ushort4*)(ab + (size_t)p0.x * D + hl * 4);
        ushort4 v1 = *(const ushort4*)(ab + (size_t)p1.x * D + hl * 4);
        float w0v = __int_as_float(p0.y), w1v = __int_as_float(p1.y);
        a0 += w0v * bf2f(v0.x) + w1v * bf2f(v1.x);
        a1 += w0v * bf2f(v0.y) + w1v * bf2f(v1.y);
        a2 += w0v * bf2f(v0.z) + w1v * bf2f(v1.z);
        a3 += w0v * bf2f(v0.w) + w1v * bf2f(v1.w);
        k += 4;
    }
    for (; k < s1; ++k) {
        if (half == 0) {
            int2 p = edges[k];
            ushort4 v = *(const ushort4*)(ab + (size_t)p.x * D + hl * 4);
            float wv = __int_as_float(p.y);
            a0 += wv * bf2f(v.x); a1 += wv * bf2f(v.y);
            a2 += wv * bf2f(v.z); a3 += wv * bf2f(v.w);
        }
    }
    a0 += __shfl_xor(a0, 32); a1 += __shfl_xor(a1, 32);
    a2 += __shfl_xor(a2, 32); a3 += __shfl_xor(a3, 32);
    if (half == 0) {
        float sw = FILLV * dinv[o + i];
        ushort4 av = *(const ushort4*)(ab + (size_t)i * D + hl * 4);
        float b0 = bf2f(av.x), b1 = bf2f(av.y), b2 = bf2f(av.z), b3 = bf2f(av.w);
        a0 += sw * b0; a1 += sw * b1; a2 += sw * b2; a3 += sw * b3;
        float w0 = wv3[0], w1 = wv3[1], w2 = wv3[2];
        float4 xv = *(const float4*)(x + (size_t)i * D + hl * 4);
        float4 ov;
        ov.x = w0 * xv.x + w1 * b0 + w2 * a0;
        ov.y = w0 * xv.y + w1 * b1 + w2 * a1;
        ov.z = w0 * xv.z + w1 * b2 + w2 * a2;
        ov.w = w0 * xv.w + w1 * b3 + w2 * a3;
        *(float4*)(out + (size_t)i * 2 * D + hoff + hl * 4) = ov;
    }
}

// ---------------------------------------------------------------------------
extern "C" void kernel_launch(void* const* d_in, const int* in_sizes, int n_in,
                              void* d_out, int out_size, void* d_ws, size_t ws_size,
                              hipStream_t stream) {
    const float* x_s = (const float*)d_in[0];
    const float* x_t = (const float*)d_in[1];
    const int*   ei  = (const int*)d_in[2];
    const float* ew  = (const float*)d_in[3];
    const float* w_s = (const float*)d_in[4];
    const float* w_t = (const float*)d_in[5];
    const int N = in_sizes[0] / D;
    const int E = in_sizes[3];
    const int* row = ei;
    const int* col = ei + E;

    const int total = 2 * N;
    const int nTiles = (total + 255) / 256;        // <= 512

    // Workspace: [dinv 2N][start 2N+2][tsum 512][toff 512][align 256]
    // [edges 2E int2 (64B-aligned for clean XCD range ownership)]
    // [xb_s ND u16][xb_t ND u16][ab_s ND u16][ab_t ND u16]
    // Padded cntp (2N*PAD ints = 6.4MB) aliases ab_s: dead before pull1.
    // ranks (E u32 = 3.2MB) lives in d_out scratch: dead before pull2 writes.
    float* f      = (float*)d_ws;
    float* dinv   = f;                              // 2N
    int*   start  = (int*)(f + (size_t)total);      // 2N+2
    int*   tsum   = start + (total + 2);
    int*   toff   = tsum + 512;
    char*  pc     = (char*)(toff + 512);
    pc = (char*)(((size_t)pc + 255) & ~(size_t)255);
    int2*  edges  = (int2*)pc;                      // 2E, 64B-aligned
    u16*   xb_s   = (u16*)(edges + 2 * (size_t)E);
    u16*   xb_t   = xb_s + (size_t)N * D;
    u16*   ab_s   = xb_t + (size_t)N * D;
    u16*   ab_t   = ab_s + (size_t)N * D;
    int*   cntp   = (int*)ab_s;                     // alias, dead before pull1
    unsigned* ranks = (unsigned*)d_out;             // scratch, dead before pull2
    float* out    = (float*)d_out;

    hipMemsetAsync(cntp, 0, (size_t)total * PAD * sizeof(int), stream);

    long long nd = (long long)N * D;
    int blkC  = (int)((nd / 2 + 255) / 256);
    int blkE  = (E + 255) / 256;
    int blk2N = (total + 255) / 256;
    tobf_kernel<<<blkC, 256, 0, stream>>>(x_s, x_t, xb_s, xb_t, nd);
    cnt_deg_kernel<<<blkE, 256, 0, stream>>>(row, col, ew, (u64*)cntp, ranks, E, N);
    invert_kernel<<<blk2N, 256, 0, stream>>>(cntp, dinv, total);
    scanA_kernel<<<nTiles, 256, 0, stream>>>(cntp, tsum, total);
    scanB_kernel<<<1, 512, 0, stream>>>(tsum, toff, nTiles);
    scanC_kernel<<<nTiles, 256, 0, stream>>>(cntp, toff, start, total, 2 * E);

    // slot-range size per XCD, multiple of 8 slots (64B lines of int2)
    int SL = ((2 * E + NXCD - 1) / NXCD + 7) & ~7;
    fillR_kernel<<<NXCD * blkE, 256, 0, stream>>>(start, row, col, ew, ranks,
                                                  dinv, edges, E, N, SL);

    long long pull_threads = (long long)total * 64;
    int blkP = (int)((pull_threads + 255) / 256);
    pull1_kernel<<<blkP, 256, 0, stream>>>(start, edges, dinv, xb_s, xb_t,
                                           x_s, x_t, ab_s, ab_t, N);
    pull2_kernel<<<blkP, 256, 0, stream>>>(start, edges, dinv, ab_s, ab_t,
                                           x_s, x_t, out, w_s, w_t, N);
}

// Round 3
// 374.776 us; speedup vs baseline: 1.2138x; 1.1442x over previous
//
#include <hip/hip_runtime.h>

#define D 128
#define FILLV 0.5f
#define PAD 16   // counters strided to 64B lines
#define NXCD 8

typedef unsigned short u16;
typedef unsigned long long u64;

__device__ __forceinline__ u16 f2bf(float f) {          // RNE fp32 -> bf16
    unsigned u = __float_as_uint(f);
    u += 0x7FFF + ((u >> 16) & 1);
    return (u16)(u >> 16);
}
__device__ __forceinline__ float bf2f(u16 h) {
    return __uint_as_float(((unsigned)h) << 16);
}

// ---------------------------------------------------------------------------
// Convert both feature matrices to bf16 staging copies (RNE).
__global__ void tobf_kernel(const float* __restrict__ x_s, const float* __restrict__ x_t,
                            u16* __restrict__ xb_s, u16* __restrict__ xb_t, long long nd) {
    long long t = (long long)blockIdx.x * blockDim.x + threadIdx.x;
    long long q = nd / 4;
    const float* x; u16* xb; long long i;
    if (t < q) { x = x_s; xb = xb_s; i = t * 4; }
    else if (t < 2 * q) { x = x_t; xb = xb_t; i = (t - q) * 4; }
    else return;
    float4 v = *(const float4*)(x + i);
    ushort4 o;
    o.x = f2bf(v.x); o.y = f2bf(v.y); o.z = f2bf(v.z); o.w = f2bf(v.w);
    *(ushort4*)(xb + i) = o;
}

// Pass 1: ONE packed 64-bit atomic per edge-direction:
//   high word += 1 (count), low word += w * 2^24 (fixed-point degree).
// The atomic RETURN's high word is this edge's within-bucket rank; save both
// ranks packed u16x2 (coalesced, nontemporal) -> downstream needs no atomics.
__global__ void cnt_deg_kernel(const int* __restrict__ row, const int* __restrict__ col,
                               const float* __restrict__ w,
                               u64* __restrict__ cntp64, unsigned* __restrict__ ranks,
                               int E, int N) {
    int e = blockIdx.x * blockDim.x + threadIdx.x;
    if (e >= E) return;
    int r = row[e], c = col[e];
    unsigned fx = (unsigned)(w[e] * 16777216.0f);       // w * 2^24
    u64 add = (1ull << 32) | fx;
    u64 oc = atomicAdd(&cntp64[(size_t)c * (PAD / 2)], add);        // s-side bucket (col)
    u64 orr = atomicAdd(&cntp64[(size_t)(N + r) * (PAD / 2)], add); // t-side bucket (N+row)
    unsigned pk = ((unsigned)(orr >> 32) << 16) | ((unsigned)(oc >> 32) & 0xffffu);
    __builtin_nontemporal_store(pk, ranks + e);
}

// Unpack: dinv[i] = 1/(deg+FILL); re-store plain count for the scan phases.
__global__ void invert_kernel(int* __restrict__ cntp, float* __restrict__ dinv, int total) {
    int i = blockIdx.x * blockDim.x + threadIdx.x;
    if (i >= total) return;
    u64 v = *(const u64*)&cntp[(size_t)i * PAD];
    float deg = (float)(unsigned)(v & 0xffffffffu) * (1.0f / 16777216.0f);
    dinv[i] = 1.0f / (deg + FILLV);
    cntp[(size_t)i * PAD] = (int)(v >> 32);
}

// --------------------------- 3-phase parallel scan --------------------------
__global__ void scanA_kernel(const int* __restrict__ cntp, int* __restrict__ tsum, int total) {
    __shared__ int sh[256];
    int gid = blockIdx.x * 256 + threadIdx.x;
    sh[threadIdx.x] = (gid < total) ? cntp[(size_t)gid * PAD] : 0;
    __syncthreads();
    for (int off = 128; off > 0; off >>= 1) {
        if (threadIdx.x < off) sh[threadIdx.x] += sh[threadIdx.x + off];
        __syncthreads();
    }
    if (threadIdx.x == 0) tsum[blockIdx.x] = sh[0];
}

__global__ void scanB_kernel(const int* __restrict__ tsum, int* __restrict__ toff, int nt) {
    __shared__ int sh[512];
    int t = threadIdx.x;
    int v = (t < nt) ? tsum[t] : 0;
    sh[t] = v;
    __syncthreads();
    for (int off = 1; off < 512; off <<= 1) {
        int u = 0;
        if (t >= off) u = sh[t - off];
        __syncthreads();
        sh[t] += u;
        __syncthreads();
    }
    if (t < nt) toff[t] = sh[t] - v;
}

__global__ void scanC_kernel(const int* __restrict__ cntp, const int* __restrict__ toff,
                             int* __restrict__ start, int total, int grand_total) {
    __shared__ int sh[256];
    int gid = blockIdx.x * 256 + threadIdx.x;
    int v = (gid < total) ? cntp[(size_t)gid * PAD] : 0;
    sh[threadIdx.x] = v;
    __syncthreads();
    for (int off = 1; off < 256; off <<= 1) {
        int u = 0;
        if (threadIdx.x >= off) u = sh[threadIdx.x - off];
        __syncthreads();
        sh[threadIdx.x] += u;
        __syncthreads();
    }
    int run = toff[blockIdx.x] + sh[threadIdx.x] - v;   // exclusive
    if (gid < total) start[gid] = run;
    if (gid == 0) start[total] = grand_total;
}

// Pass 2a (once, non-redundant): do ALL per-edge gathers exactly once and emit
// coalesced record streams: packed slots (ss,st) and the two int2 payloads.
// slot = start[bucket] + rank (no atomics). Streams live in d_out scratch.
__global__ void slot_kernel(const int* __restrict__ start,
                            const int* __restrict__ row, const int* __restrict__ col,
                            const float* __restrict__ w, const unsigned* __restrict__ ranks,
                            const float* __restrict__ dinv,
                            u64* __restrict__ ssst, u64* __restrict__ es, u64* __restrict__ et,
                            int E, int N) {
    int e = blockIdx.x * blockDim.x + threadIdx.x;
    if (e >= E) return;
    int r = row[e], c = col[e];
    float we = w[e];
    unsigned pk = __builtin_nontemporal_load(ranks + e);
    int ss = start[c] + (int)(pk & 0xffffu);        // s-side slot (bucket col)
    int st = start[N + r] + (int)(pk >> 16);        // t-side slot (bucket N+row)
    float wns = we * dinv[N + r];                   // s-side: normalize by deg_s (row key)
    float wnt = we * dinv[c];                       // t-side: normalize by deg_t (col key)
    u64 sv = ((u64)(unsigned)st << 32) | (unsigned)ss;
    u64 ev = ((u64)__float_as_uint(wns) << 32) | (unsigned)r;   // int2{x=r, y=wns}
    u64 tv = ((u64)__float_as_uint(wnt) << 32) | (unsigned)c;   // int2{x=c, y=wnt}
    __builtin_nontemporal_store(sv, ssst + e);
    __builtin_nontemporal_store(ev, es + e);
    __builtin_nontemporal_store(tv, et + e);
}

// Pass 2b: XCD-range-partitioned filter scatter. ZERO gathers, ZERO atomics —
// pure sequential nontemporal streaming of the precomputed records. Slot space
// [0,2E) split into NXCD contiguous 64B-aligned ranges; blocks with
// blockIdx&7 == rid land on XCD rid (round-robin dispatch) and write ONLY
// slots in their range -> the ~8 payloads sharing a 64B line merge in ONE
// XCD's L2. Payload loads are predicated: lines with no in-range record for a
// given XCD are never fetched. Slots are a permutation of [0,2E), so each
// record is written by exactly one XCD.
__global__ void fillX_kernel(const u64* __restrict__ ssst,
                             const u64* __restrict__ es, const u64* __restrict__ et,
                             u64* __restrict__ edges, int E, int SL) {
    int e = (int)(blockIdx.x >> 3) * blockDim.x + threadIdx.x;
    int rid = blockIdx.x & 7;
    if (e >= E) return;
    int lo = rid * SL, hi = lo + SL;
    u64 sv = __builtin_nontemporal_load(ssst + e);
    int ss = (int)(unsigned)(sv & 0xffffffffu);
    int st = (int)(unsigned)(sv >> 32);
    bool ds = (ss >= lo) & (ss < hi);
    bool dt = (st >= lo) & (st < hi);
    if (ds) {
        u64 ev = __builtin_nontemporal_load(es + e);
        edges[ss] = ev;
    }
    if (dt) {
        u64 tv = __builtin_nontemporal_load(et + e);
        edges[st] = tv;
    }
}

// ---------------------------------------------------------------------------
// Pull kernels: wave per bucket; HALF-WAVE per edge (bf16 row = 256B = 32
// lanes x ushort4). Main loop: 8 edges/iter (4 per half, 4 gathers in flight);
// mid step 4; tail by half 0. Payload loads are wave-uniform -> s_load.
__global__ void pull1_kernel(const int* __restrict__ start, const int2* __restrict__ edges,
                             const float* __restrict__ dinv,
                             const u16* __restrict__ xb_s, const u16* __restrict__ xb_t,
                             const float* __restrict__ x_s, const float* __restrict__ x_t,
                             u16* __restrict__ ab_s, u16* __restrict__ ab_t, int N) {
    int wid0 = (int)(((long long)blockIdx.x * blockDim.x + threadIdx.x) >> 6);
    int wid = __builtin_amdgcn_readfirstlane(wid0);
    int lane = threadIdx.x & 63;
    int half = lane >> 5, hl = lane & 31;
    if (wid >= 2 * N) return;
    const u16* xb; const float* x; u16* ab; int i, o;
    if (wid < N) { i = wid;     o = N; xb = xb_s; x = x_s; ab = ab_s; }
    else         { i = wid - N; o = 0; xb = xb_t; x = x_t; ab = ab_t; }
    int s0 = start[wid], s1 = start[wid + 1];
    float a0 = 0.f, a1 = 0.f, a2 = 0.f, a3 = 0.f;
    int k = s0;
    for (; k + 8 <= s1; k += 8) {
        int b = k + 4 * half;
        int2 p0 = edges[b], p1 = edges[b + 1], p2 = edges[b + 2], p3 = edges[b + 3];
        ushort4 v0 = *(const ushort4*)(xb + (size_t)p0.x * D + hl * 4);
        ushort4 v1 = *(const ushort4*)(xb + (size_t)p1.x * D + hl * 4);
        ushort4 v2 = *(const ushort4*)(xb + (size_t)p2.x * D + hl * 4);
        ushort4 v3 = *(const ushort4*)(xb + (size_t)p3.x * D + hl * 4);
        float w0v = __int_as_float(p0.y), w1v = __int_as_float(p1.y);
        float w2v = __int_as_float(p2.y), w3v = __int_as_float(p3.y);
        a0 += w0v * bf2f(v0.x) + w1v * bf2f(v1.x) + w2v * bf2f(v2.x) + w3v * bf2f(v3.x);
        a1 += w0v * bf2f(v0.y) + w1v * bf2f(v1.y) + w2v * bf2f(v2.y) + w3v * bf2f(v3.y);
        a2 += w0v * bf2f(v0.z) + w1v * bf2f(v1.z) + w2v * bf2f(v2.z) + w3v * bf2f(v3.z);
        a3 += w0v * bf2f(v0.w) + w1v * bf2f(v1.w) + w2v * bf2f(v2.w) + w3v * bf2f(v3.w);
    }
    if (k + 4 <= s1) {
        int b = k + 2 * half;
        int2 p0 = edges[b], p1 = edges[b + 1];
        ushort4 v0 = *(const ushort4*)(xb + (size_t)p0.x * D + hl * 4);
        ushort4 v1 = *(const ushort4*)(xb + (size_t)p1.x * D + hl * 4);
        float w0v = __int_as_float(p0.y), w1v = __int_as_float(p1.y);
        a0 += w0v * bf2f(v0.x) + w1v * bf2f(v1.x);
        a1 += w0v * bf2f(v0.y) + w1v * bf2f(v1.y);
        a2 += w0v * bf2f(v0.z) + w1v * bf2f(v1.z);
        a3 += w0v * bf2f(v0.w) + w1v * bf2f(v1.w);
        k += 4;
    }
    for (; k < s1; ++k) {
        if (half == 0) {
            int2 p = edges[k];
            ushort4 v = *(const ushort4*)(xb + (size_t)p.x * D + hl * 4);
            float wv = __int_as_float(p.y);
            a0 += wv * bf2f(v.x); a1 += wv * bf2f(v.y);
            a2 += wv * bf2f(v.z); a3 += wv * bf2f(v.w);
        }
    }
    a0 += __shfl_xor(a0, 32); a1 += __shfl_xor(a1, 32);
    a2 += __shfl_xor(a2, 32); a3 += __shfl_xor(a3, 32);
    if (half == 0) {
        float sw = FILLV * dinv[o + i];
        float4 xv = *(const float4*)(x + (size_t)i * D + hl * 4);
        a0 += sw * xv.x; a1 += sw * xv.y; a2 += sw * xv.z; a3 += sw * xv.w;
        ushort4 ov;
        ov.x = f2bf(a0); ov.y = f2bf(a1); ov.z = f2bf(a2); ov.w = f2bf(a3);
        *(ushort4*)(ab + (size_t)i * D + hl * 4) = ov;
    }
}

// Hop-2 pull + fused epilogue: out_half = w0*x + w1*a + w2*(conv(a)).
__global__ void pull2_kernel(const int* __restrict__ start, const int2* __restrict__ edges,
                             const float* __restrict__ dinv,
                             const u16* __restrict__ ab_s, const u16* __restrict__ ab_t,
                             const float* __restrict__ x_s, const float* __restrict__ x_t,
                             float* __restrict__ out,
                             const float* __restrict__ w_s, const float* __restrict__ w_t, int N) {
    int wid0 = (int)(((long long)blockIdx.x * blockDim.x + threadIdx.x) >> 6);
    int wid = __builtin_amdgcn_readfirstlane(wid0);
    int lane = threadIdx.x & 63;
    int half = lane >> 5, hl = lane & 31;
    if (wid >= 2 * N) return;
    const u16* ab; const float* x; const float* wv3; int i, o, hoff;
    if (wid < N) { i = wid;     o = N; ab = ab_s; x = x_s; wv3 = w_s; hoff = 0; }
    else         { i = wid - N; o = 0; ab = ab_t; x = x_t; wv3 = w_t; hoff = D; }
    int s0 = start[wid], s1 = start[wid + 1];
    float a0 = 0.f, a1 = 0.f, a2 = 0.f, a3 = 0.f;
    int k = s0;
    for (; k + 8 <= s1; k += 8) {
        int b = k + 4 * half;
        int2 p0 = edges[b], p1 = edges[b + 1], p2 = edges[b + 2], p3 = edges[b + 3];
        ushort4 v0 = *(const ushort4*)(ab + (size_t)p0.x * D + hl * 4);
        ushort4 v1 = *(const ushort4*)(ab + (size_t)p1.x * D + hl * 4);
        ushort4 v2 = *(const ushort4*)(ab + (size_t)p2.x * D + hl * 4);
        ushort4 v3 = *(const ushort4*)(ab + (size_t)p3.x * D + hl * 4);
        float w0v = __int_as_float(p0.y), w1v = __int_as_float(p1.y);
        float w2v = __int_as_float(p2.y), w3v = __int_as_float(p3.y);
        a0 += w0v * bf2f(v0.x) + w1v * bf2f(v1.x) + w2v * bf2f(v2.x) + w3v * bf2f(v3.x);
        a1 += w0v * bf2f(v0.y) + w1v * bf2f(v1.y) + w2v * bf2f(v2.y) + w3v * bf2f(v3.y);
        a2 += w0v * bf2f(v0.z) + w1v * bf2f(v1.z) + w2v * bf2f(v2.z) + w3v * bf2f(v3.z);
        a3 += w0v * bf2f(v0.w) + w1v * bf2f(v1.w) + w2v * bf2f(v2.w) + w3v * bf2f(v3.w);
    }
    if (k + 4 <= s1) {
        int b = k + 2 * half;
        int2 p0 = edges[b], p1 = edges[b + 1];
        ushort4 v0 = *(const ushort4*)(ab + (size_t)p0.x * D + hl * 4);
        ushort4 v1 = *(const ushort4*)(ab + (size_t)p1.x * D + hl * 4);
        float w0v = __int_as_float(p0.y), w1v = __int_as_float(p1.y);
        a0 += w0v * bf2f(v0.x) + w1v * bf2f(v1.x);
        a1 += w0v * bf2f(v0.y) + w1v * bf2f(v1.y);
        a2 += w0v * bf2f(v0.z) + w1v * bf2f(v1.z);
        a3 += w0v * bf2f(v0.w) + w1v * bf2f(v1.w);
        k += 4;
    }
    for (; k < s1; ++k) {
        if (half == 0) {
            int2 p = edges[k];
            ushort4 v = *(const ushort4*)(ab + (size_t)p.x * D + hl * 4);
            float wv = __int_as_float(p.y);
            a0 += wv * bf2f(v.x); a1 += wv * bf2f(v.y);
            a2 += wv * bf2f(v.z); a3 += wv * bf2f(v.w);
        }
    }
    a0 += __shfl_xor(a0, 32); a1 += __shfl_xor(a1, 32);
    a2 += __shfl_xor(a2, 32); a3 += __shfl_xor(a3, 32);
    if (half == 0) {
        float sw = FILLV * dinv[o + i];
        ushort4 av = *(const ushort4*)(ab + (size_t)i * D + hl * 4);
        float b0 = bf2f(av.x), b1 = bf2f(av.y), b2 = bf2f(av.z), b3 = bf2f(av.w);
        a0 += sw * b0; a1 += sw * b1; a2 += sw * b2; a3 += sw * b3;
        float w0 = wv3[0], w1 = wv3[1], w2 = wv3[2];
        float4 xv = *(const float4*)(x + (size_t)i * D + hl * 4);
        float4 ov;
        ov.x = w0 * xv.x + w1 * b0 + w2 * a0;
        ov.y = w0 * xv.y + w1 * b1 + w2 * a1;
        ov.z = w0 * xv.z + w1 * b2 + w2 * a2;
        ov.w = w0 * xv.w + w1 * b3 + w2 * a3;
        *(float4*)(out + (size_t)i * 2 * D + hoff + hl * 4) = ov;
    }
}

// ---------------------------------------------------------------------------
extern "C" void kernel_launch(void* const* d_in, const int* in_sizes, int n_in,
                              void* d_out, int out_size, void* d_ws, size_t ws_size,
                              hipStream_t stream) {
    const float* x_s = (const float*)d_in[0];
    const float* x_t = (const float*)d_in[1];
    const int*   ei  = (const int*)d_in[2];
    const float* ew  = (const float*)d_in[3];
    const float* w_s = (const float*)d_in[4];
    const float* w_t = (const float*)d_in[5];
    const int N = in_sizes[0] / D;
    const int E = in_sizes[3];
    const int* row = ei;
    const int* col = ei + E;

    const int total = 2 * N;
    const int nTiles = (total + 255) / 256;        // <= 512

    // Workspace (d_ws): [dinv 2N][start 2N+2][tsum 512][toff 512][align]
    // [edges 2E int2 (64B-aligned)] [xb_s ND u16][xb_t ND u16][ab_s][ab_t]
    // Padded cntp (2N*PAD ints = 6.4MB) aliases ab_s: dead before pull1.
    float* f      = (float*)d_ws;
    float* dinv   = f;                              // 2N
    int*   start  = (int*)(f + (size_t)total);      // 2N+2
    int*   tsum   = start + (total + 2);
    int*   toff   = tsum + 512;
    char*  pc     = (char*)(toff + 512);
    pc = (char*)(((size_t)pc + 255) & ~(size_t)255);
    u64*   edges  = (u64*)pc;                       // 2E int2, 64B-aligned
    u16*   xb_s   = (u16*)(edges + 2 * (size_t)E);
    u16*   xb_t   = xb_s + (size_t)N * D;
    u16*   ab_s   = xb_t + (size_t)N * D;
    u16*   ab_t   = ab_s + (size_t)N * D;
    int*   cntp   = (int*)ab_s;                     // alias, dead before pull1

    // d_out scratch (dead until pull2 writes): ranks[E] u32, then the three
    // record streams ssst/es/et (u64[E] each), 8B-aligned. Total ~28E bytes.
    unsigned* ranks = (unsigned*)d_out;
    char* po = (char*)d_out + (((size_t)E * 4 + 7) & ~(size_t)7);
    u64* ssst = (u64*)po;
    u64* es   = ssst + (size_t)E;
    u64* et   = es + (size_t)E;
    float* out = (float*)d_out;

    hipMemsetAsync(cntp, 0, (size_t)total * PAD * sizeof(int), stream);

    long long nd = (long long)N * D;
    int blkC  = (int)((nd / 2 + 255) / 256);
    int blkE  = (E + 255) / 256;
    int blk2N = (total + 255) / 256;
    tobf_kernel<<<blkC, 256, 0, stream>>>(x_s, x_t, xb_s, xb_t, nd);
    cnt_deg_kernel<<<blkE, 256, 0, stream>>>(row, col, ew, (u64*)cntp, ranks, E, N);
    invert_kernel<<<blk2N, 256, 0, stream>>>(cntp, dinv, total);
    scanA_kernel<<<nTiles, 256, 0, stream>>>(cntp, tsum, total);
    scanB_kernel<<<1, 512, 0, stream>>>(tsum, toff, nTiles);
    scanC_kernel<<<nTiles, 256, 0, stream>>>(cntp, toff, start, total, 2 * E);

    slot_kernel<<<blkE, 256, 0, stream>>>(start, row, col, ew, ranks, dinv,
                                          ssst, es, et, E, N);

    // slot-range size per XCD, multiple of 8 slots (64B lines of int2)
    int SL = ((2 * E + NXCD - 1) / NXCD + 7) & ~7;
    fillX_kernel<<<NXCD * blkE, 256, 0, stream>>>(ssst, es, et, edges, E, SL);

    long long pull_threads = (long long)total * 64;
    int blkP = (int)((pull_threads + 255) / 256);
    pull1_kernel<<<blkP, 256, 0, stream>>>(start, (const int2*)edges, dinv, xb_s, xb_t,
                                           x_s, x_t, ab_s, ab_t, N);
    pull2_kernel<<<blkP, 256, 0, stream>>>(start, (const int2*)edges, dinv, ab_s, ab_t,
                                           x_s, x_t, out, w_s, w_t, N);
}

// Round 4
// 366.582 us; speedup vs baseline: 1.2409x; 1.0224x over previous
//
#include <hip/hip_runtime.h>

#define D 128
#define FILLV 0.5f
#define PAD 2    // u64 counter per bucket, CONTIGUOUS (8 buckets/64B line).
                 // 64B padding was only needed when fill bumped cursors; now
                 // the table is touched only by cnt/scan -> small footprint
                 // keeps lines resident at the atomic point (WRITE 53MB->~1MB).
#define NXCD 8

typedef unsigned short u16;
typedef unsigned long long u64;

__device__ __forceinline__ u16 f2bf(float f) {          // RNE fp32 -> bf16
    unsigned u = __float_as_uint(f);
    u += 0x7FFF + ((u >> 16) & 1);
    return (u16)(u >> 16);
}
__device__ __forceinline__ float bf2f(u16 h) {
    return __uint_as_float(((unsigned)h) << 16);
}

// ---------------------------------------------------------------------------
// FUSED pass 1: edge blocks (first, so atomics start earliest) do ONE packed
// 64-bit atomic per edge-direction: high word += 1 (count), low word +=
// w * 2^24 (fixed-point degree; < 2^32 for max degree << 256). The atomic
// RETURN's high word is this edge's within-bucket rank; both ranks packed
// u16x2, stored coalesced+nontemporal. Conversion blocks (after) stream the
// fp32->bf16 staging copies — pure-BW work hidden under atomic latency.
__global__ void cnt_tobf_kernel(const int* __restrict__ row, const int* __restrict__ col,
                                const float* __restrict__ w,
                                u64* __restrict__ cntp64, unsigned* __restrict__ ranks,
                                const float* __restrict__ x_s, const float* __restrict__ x_t,
                                u16* __restrict__ xb_s, u16* __restrict__ xb_t,
                                int E, int N, int blkE, long long nd) {
    if ((int)blockIdx.x < blkE) {
        int e = blockIdx.x * 256 + threadIdx.x;
        if (e >= E) return;
        int r = row[e], c = col[e];
        unsigned fx = (unsigned)(w[e] * 16777216.0f);       // w * 2^24
        u64 add = (1ull << 32) | fx;
        u64 oc  = atomicAdd(&cntp64[(size_t)c], add);       // s-side bucket (col)
        u64 orr = atomicAdd(&cntp64[(size_t)N + r], add);   // t-side bucket (N+row)
        unsigned pk = ((unsigned)(orr >> 32) << 16) | ((unsigned)(oc >> 32) & 0xffffu);
        __builtin_nontemporal_store(pk, ranks + e);
    } else {
        long long t = (long long)(blockIdx.x - blkE) * 256 + threadIdx.x;
        long long q = nd / 4;
        const float* x; u16* xb; long long i;
        if (t < q) { x = x_s; xb = xb_s; i = t * 4; }
        else if (t < 2 * q) { x = x_t; xb = xb_t; i = (t - q) * 4; }
        else return;
        float4 v = *(const float4*)(x + i);
        ushort4 o;
        o.x = f2bf(v.x); o.y = f2bf(v.y); o.z = f2bf(v.z); o.w = f2bf(v.w);
        *(ushort4*)(xb + i) = o;
    }
}

// -------------------- fused invert + scan phase A ---------------------------
// Unpack packed counter: dinv[i] = 1/(deg+FILL); re-store plain count (read
// again by scanC); block-reduce counts into tsum.
__global__ void scanAI_kernel(int* __restrict__ cntp, float* __restrict__ dinv,
                              int* __restrict__ tsum, int total) {
    __shared__ int sh[256];
    int gid = blockIdx.x * 256 + threadIdx.x;
    int cnt = 0;
    if (gid < total) {
        u64 v = *(const u64*)&cntp[(size_t)gid * PAD];
        float deg = (float)(unsigned)(v & 0xffffffffu) * (1.0f / 16777216.0f);
        dinv[gid] = 1.0f / (deg + FILLV);
        cnt = (int)(v >> 32);
        cntp[(size_t)gid * PAD] = cnt;
    }
    sh[threadIdx.x] = cnt;
    __syncthreads();
    for (int off = 128; off > 0; off >>= 1) {
        if (threadIdx.x < off) sh[threadIdx.x] += sh[threadIdx.x + off];
        __syncthreads();
    }
    if (threadIdx.x == 0) tsum[blockIdx.x] = sh[0];
}

__global__ void scanB_kernel(const int* __restrict__ tsum, int* __restrict__ toff, int nt) {
    __shared__ int sh[512];
    int t = threadIdx.x;
    int v = (t < nt) ? tsum[t] : 0;
    sh[t] = v;
    __syncthreads();
    for (int off = 1; off < 512; off <<= 1) {
        int u = 0;
        if (t >= off) u = sh[t - off];
        __syncthreads();
        sh[t] += u;
        __syncthreads();
    }
    if (t < nt) toff[t] = sh[t] - v;
}

__global__ void scanC_kernel(const int* __restrict__ cntp, const int* __restrict__ toff,
                             int* __restrict__ start, int total, int grand_total) {
    __shared__ int sh[256];
    int gid = blockIdx.x * 256 + threadIdx.x;
    int v = (gid < total) ? cntp[(size_t)gid * PAD] : 0;
    sh[threadIdx.x] = v;
    __syncthreads();
    for (int off = 1; off < 256; off <<= 1) {
        int u = 0;
        if (threadIdx.x >= off) u = sh[threadIdx.x - off];
        __syncthreads();
        sh[threadIdx.x] += u;
        __syncthreads();
    }
    int run = toff[blockIdx.x] + sh[threadIdx.x] - v;   // exclusive
    if (gid < total) start[gid] = run;
    if (gid == 0) start[total] = grand_total;
}

// Pass 2a (once, non-redundant): do ALL per-edge gathers exactly once and emit
// coalesced record streams: packed slots (ss,st) and the two int2 payloads.
// slot = start[bucket] + rank (no atomics). Streams live in d_out scratch.
__global__ void slot_kernel(const int* __restrict__ start,
                            const int* __restrict__ row, const int* __restrict__ col,
                            const float* __restrict__ w, const unsigned* __restrict__ ranks,
                            const float* __restrict__ dinv,
                            u64* __restrict__ ssst, u64* __restrict__ es, u64* __restrict__ et,
                            int E, int N) {
    int e = blockIdx.x * blockDim.x + threadIdx.x;
    if (e >= E) return;
    int r = row[e], c = col[e];
    float we = w[e];
    unsigned pk = __builtin_nontemporal_load(ranks + e);
    int ss = start[c] + (int)(pk & 0xffffu);        // s-side slot (bucket col)
    int st = start[N + r] + (int)(pk >> 16);        // t-side slot (bucket N+row)
    float wns = we * dinv[N + r];                   // s-side: normalize by deg_s (row key)
    float wnt = we * dinv[c];                       // t-side: normalize by deg_t (col key)
    u64 sv = ((u64)(unsigned)st << 32) | (unsigned)ss;
    u64 ev = ((u64)__float_as_uint(wns) << 32) | (unsigned)r;   // int2{x=r, y=wns}
    u64 tv = ((u64)__float_as_uint(wnt) << 32) | (unsigned)c;   // int2{x=c, y=wnt}
    __builtin_nontemporal_store(sv, ssst + e);
    __builtin_nontemporal_store(ev, es + e);
    __builtin_nontemporal_store(tv, et + e);
}

// Pass 2b: XCD-range-partitioned filter scatter. ZERO gathers, ZERO atomics —
// pure sequential nontemporal streaming of the precomputed records. Slot space
// [0,2E) split into NXCD contiguous 64B-aligned ranges; blocks with
// blockIdx&7 == rid land on XCD rid (round-robin dispatch) and write ONLY
// slots in their range -> the ~8 payloads sharing a 64B line merge in ONE
// XCD's L2. Payload loads are predicated: lines with no in-range record for a
// given XCD are never fetched. Slots are a permutation of [0,2E), so each
// record is written by exactly one XCD.
__global__ void fillX_kernel(const u64* __restrict__ ssst,
                             const u64* __restrict__ es, const u64* __restrict__ et,
                             u64* __restrict__ edges, int E, int SL) {
    int e = (int)(blockIdx.x >> 3) * blockDim.x + threadIdx.x;
    int rid = blockIdx.x & 7;
    if (e >= E) return;
    int lo = rid * SL, hi = lo + SL;
    u64 sv = __builtin_nontemporal_load(ssst + e);
    int ss = (int)(unsigned)(sv & 0xffffffffu);
    int st = (int)(unsigned)(sv >> 32);
    bool ds = (ss >= lo) & (ss < hi);
    bool dt = (st >= lo) & (st < hi);
    if (ds) {
        u64 ev = __builtin_nontemporal_load(es + e);
        edges[ss] = ev;
    }
    if (dt) {
        u64 tv = __builtin_nontemporal_load(et + e);
        edges[st] = tv;
    }
}

// ---------------------------------------------------------------------------
// Pull kernels: wave per bucket; HALF-WAVE per edge (bf16 row = 256B = 32
// lanes x ushort4). Main loop: 8 edges/iter (4 per half, 4 gathers in flight);
// mid step 4; tail by half 0. Payload loads are wave-uniform -> s_load.
__global__ void pull1_kernel(const int* __restrict__ start, const int2* __restrict__ edges,
                             const float* __restrict__ dinv,
                             const u16* __restrict__ xb_s, const u16* __restrict__ xb_t,
                             const float* __restrict__ x_s, const float* __restrict__ x_t,
                             u16* __restrict__ ab_s, u16* __restrict__ ab_t, int N) {
    int wid0 = (int)(((long long)blockIdx.x * blockDim.x + threadIdx.x) >> 6);
    int wid = __builtin_amdgcn_readfirstlane(wid0);
    int lane = threadIdx.x & 63;
    int half = lane >> 5, hl = lane & 31;
    if (wid >= 2 * N) return;
    const u16* xb; const float* x; u16* ab; int i, o;
    if (wid < N) { i = wid;     o = N; xb = xb_s; x = x_s; ab = ab_s; }
    else         { i = wid - N; o = 0; xb = xb_t; x = x_t; ab = ab_t; }
    int s0 = start[wid], s1 = start[wid + 1];
    float a0 = 0.f, a1 = 0.f, a2 = 0.f, a3 = 0.f;
    int k = s0;
    for (; k + 8 <= s1; k += 8) {
        int b = k + 4 * half;
        int2 p0 = edges[b], p1 = edges[b + 1], p2 = edges[b + 2], p3 = edges[b + 3];
        ushort4 v0 = *(const ushort4*)(xb + (size_t)p0.x * D + hl * 4);
        ushort4 v1 = *(const ushort4*)(xb + (size_t)p1.x * D + hl * 4);
        ushort4 v2 = *(const ushort4*)(xb + (size_t)p2.x * D + hl * 4);
        ushort4 v3 = *(const ushort4*)(xb + (size_t)p3.x * D + hl * 4);
        float w0v = __int_as_float(p0.y), w1v = __int_as_float(p1.y);
        float w2v = __int_as_float(p2.y), w3v = __int_as_float(p3.y);
        a0 += w0v * bf2f(v0.x) + w1v * bf2f(v1.x) + w2v * bf2f(v2.x) + w3v * bf2f(v3.x);
        a1 += w0v * bf2f(v0.y) + w1v * bf2f(v1.y) + w2v * bf2f(v2.y) + w3v * bf2f(v3.y);
        a2 += w0v * bf2f(v0.z) + w1v * bf2f(v1.z) + w2v * bf2f(v2.z) + w3v * bf2f(v3.z);
        a3 += w0v * bf2f(v0.w) + w1v * bf2f(v1.w) + w2v * bf2f(v2.w) + w3v * bf2f(v3.w);
    }
    if (k + 4 <= s1) {
        int b = k + 2 * half;
        int2 p0 = edges[b], p1 = edges[b + 1];
        ushort4 v0 = *(const ushort4*)(xb + (size_t)p0.x * D + hl * 4);
        ushort4 v1 = *(const ushort4*)(xb + (size_t)p1.x * D + hl * 4);
        float w0v = __int_as_float(p0.y), w1v = __int_as_float(p1.y);
        a0 += w0v * bf2f(v0.x) + w1v * bf2f(v1.x);
        a1 += w0v * bf2f(v0.y) + w1v * bf2f(v1.y);
        a2 += w0v * bf2f(v0.z) + w1v * bf2f(v1.z);
        a3 += w0v * bf2f(v0.w) + w1v * bf2f(v1.w);
        k += 4;
    }
    for (; k < s1; ++k) {
        if (half == 0) {
            int2 p = edges[k];
            ushort4 v = *(const ushort4*)(xb + (size_t)p.x * D + hl * 4);
            float wv = __int_as_float(p.y);
            a0 += wv * bf2f(v.x); a1 += wv * bf2f(v.y);
            a2 += wv * bf2f(v.z); a3 += wv * bf2f(v.w);
        }
    }
    a0 += __shfl_xor(a0, 32); a1 += __shfl_xor(a1, 32);
    a2 += __shfl_xor(a2, 32); a3 += __shfl_xor(a3, 32);
    if (half == 0) {
        float sw = FILLV * dinv[o + i];
        float4 xv = *(const float4*)(x + (size_t)i * D + hl * 4);
        a0 += sw * xv.x; a1 += sw * xv.y; a2 += sw * xv.z; a3 += sw * xv.w;
        ushort4 ov;
        ov.x = f2bf(a0); ov.y = f2bf(a1); ov.z = f2bf(a2); ov.w = f2bf(a3);
        *(ushort4*)(ab + (size_t)i * D + hl * 4) = ov;
    }
}

// Hop-2 pull + fused epilogue: out_half = w0*x + w1*a + w2*(conv(a)).
__global__ void pull2_kernel(const int* __restrict__ start, const int2* __restrict__ edges,
                             const float* __restrict__ dinv,
                             const u16* __restrict__ ab_s, const u16* __restrict__ ab_t,
                             const float* __restrict__ x_s, const float* __restrict__ x_t,
                             float* __restrict__ out,
                             const float* __restrict__ w_s, const float* __restrict__ w_t, int N) {
    int wid0 = (int)(((long long)blockIdx.x * blockDim.x + threadIdx.x) >> 6);
    int wid = __builtin_amdgcn_readfirstlane(wid0);
    int lane = threadIdx.x & 63;
    int half = lane >> 5, hl = lane & 31;
    if (wid >= 2 * N) return;
    const u16* ab; const float* x; const float* wv3; int i, o, hoff;
    if (wid < N) { i = wid;     o = N; ab = ab_s; x = x_s; wv3 = w_s; hoff = 0; }
    else         { i = wid - N; o = 0; ab = ab_t; x = x_t; wv3 = w_t; hoff = D; }
    int s0 = start[wid], s1 = start[wid + 1];
    float a0 = 0.f, a1 = 0.f, a2 = 0.f, a3 = 0.f;
    int k = s0;
    for (; k + 8 <= s1; k += 8) {
        int b = k + 4 * half;
        int2 p0 = edges[b], p1 = edges[b + 1], p2 = edges[b + 2], p3 = edges[b + 3];
        ushort4 v0 = *(const ushort4*)(ab + (size_t)p0.x * D + hl * 4);
        ushort4 v1 = *(const ushort4*)(ab + (size_t)p1.x * D + hl * 4);
        ushort4 v2 = *(const ushort4*)(ab + (size_t)p2.x * D + hl * 4);
        ushort4 v3 = *(const ushort4*)(ab + (size_t)p3.x * D + hl * 4);
        float w0v = __int_as_float(p0.y), w1v = __int_as_float(p1.y);
        float w2v = __int_as_float(p2.y), w3v = __int_as_float(p3.y);
        a0 += w0v * bf2f(v0.x) + w1v * bf2f(v1.x) + w2v * bf2f(v2.x) + w3v * bf2f(v3.x);
        a1 += w0v * bf2f(v0.y) + w1v * bf2f(v1.y) + w2v * bf2f(v2.y) + w3v * bf2f(v3.y);
        a2 += w0v * bf2f(v0.z) + w1v * bf2f(v1.z) + w2v * bf2f(v2.z) + w3v * bf2f(v3.z);
        a3 += w0v * bf2f(v0.w) + w1v * bf2f(v1.w) + w2v * bf2f(v2.w) + w3v * bf2f(v3.w);
    }
    if (k + 4 <= s1) {
        int b = k + 2 * half;
        int2 p0 = edges[b], p1 = edges[b + 1];
        ushort4 v0 = *(const ushort4*)(ab + (size_t)p0.x * D + hl * 4);
        ushort4 v1 = *(const ushort4*)(ab + (size_t)p1.x * D + hl * 4);
        float w0v = __int_as_float(p0.y), w1v = __int_as_float(p1.y);
        a0 += w0v * bf2f(v0.x) + w1v * bf2f(v1.x);
        a1 += w0v * bf2f(v0.y) + w1v * bf2f(v1.y);
        a2 += w0v * bf2f(v0.z) + w1v * bf2f(v1.z);
        a3 += w0v * bf2f(v0.w) + w1v * bf2f(v1.w);
        k += 4;
    }
    for (; k < s1; ++k) {
        if (half == 0) {
            int2 p = edges[k];
            ushort4 v = *(const ushort4*)(ab + (size_t)p.x * D + hl * 4);
            float wv = __int_as_float(p.y);
            a0 += wv * bf2f(v.x); a1 += wv * bf2f(v.y);
            a2 += wv * bf2f(v.z); a3 += wv * bf2f(v.w);
        }
    }
    a0 += __shfl_xor(a0, 32); a1 += __shfl_xor(a1, 32);
    a2 += __shfl_xor(a2, 32); a3 += __shfl_xor(a3, 32);
    if (half == 0) {
        float sw = FILLV * dinv[o + i];
        ushort4 av = *(const ushort4*)(ab + (size_t)i * D + hl * 4);
        float b0 = bf2f(av.x), b1 = bf2f(av.y), b2 = bf2f(av.z), b3 = bf2f(av.w);
        a0 += sw * b0; a1 += sw * b1; a2 += sw * b2; a3 += sw * b3;
        float w0 = wv3[0], w1 = wv3[1], w2 = wv3[2];
        float4 xv = *(const float4*)(x + (size_t)i * D + hl * 4);
        float4 ov;
        ov.x = w0 * xv.x + w1 * b0 + w2 * a0;
        ov.y = w0 * xv.y + w1 * b1 + w2 * a1;
        ov.z = w0 * xv.z + w1 * b2 + w2 * a2;
        ov.w = w0 * xv.w + w1 * b3 + w2 * a3;
        *(float4*)(out + (size_t)i * 2 * D + hoff + hl * 4) = ov;
    }
}

// ---------------------------------------------------------------------------
extern "C" void kernel_launch(void* const* d_in, const int* in_sizes, int n_in,
                              void* d_out, int out_size, void* d_ws, size_t ws_size,
                              hipStream_t stream) {
    const float* x_s = (const float*)d_in[0];
    const float* x_t = (const float*)d_in[1];
    const int*   ei  = (const int*)d_in[2];
    const float* ew  = (const float*)d_in[3];
    const float* w_s = (const float*)d_in[4];
    const float* w_t = (const float*)d_in[5];
    const int N = in_sizes[0] / D;
    const int E = in_sizes[3];
    const int* row = ei;
    const int* col = ei + E;

    const int total = 2 * N;
    const int nTiles = (total + 255) / 256;        // <= 512

    // Workspace (d_ws): [dinv 2N][start 2N+2][tsum 512][toff 512][align]
    // [edges 2E int2 (64B-aligned)] [xb_s ND u16][xb_t ND u16][ab_s][ab_t]
    // Packed cntp (2N*PAD ints = 800KB) aliases ab_s: dead before pull1.
    float* f      = (float*)d_ws;
    float* dinv   = f;                              // 2N
    int*   start  = (int*)(f + (size_t)total);      // 2N+2
    int*   tsum   = start + (total + 2);
    int*   toff   = tsum + 512;
    char*  pc     = (char*)(toff + 512);
    pc = (char*)(((size_t)pc + 255) & ~(size_t)255);
    u64*   edges  = (u64*)pc;                       // 2E int2, 64B-aligned
    u16*   xb_s   = (u16*)(edges + 2 * (size_t)E);
    u16*   xb_t   = xb_s + (size_t)N * D;
    u16*   ab_s   = xb_t + (size_t)N * D;
    u16*   ab_t   = ab_s + (size_t)N * D;
    int*   cntp   = (int*)ab_s;                     // alias, dead before pull1

    // d_out scratch (dead until pull2 writes): ranks[E] u32, then the three
    // record streams ssst/es/et (u64[E] each), 8B-aligned. Total ~28E bytes.
    unsigned* ranks = (unsigned*)d_out;
    char* po = (char*)d_out + (((size_t)E * 4 + 7) & ~(size_t)7);
    u64* ssst = (u64*)po;
    u64* es   = ssst + (size_t)E;
    u64* et   = es + (size_t)E;
    float* out = (float*)d_out;

    hipMemsetAsync(cntp, 0, (size_t)total * PAD * sizeof(int), stream);

    long long nd = (long long)N * D;
    int blkC  = (int)((nd / 2 + 255) / 256);
    int blkE  = (E + 255) / 256;
    cnt_tobf_kernel<<<blkE + blkC, 256, 0, stream>>>(row, col, ew, (u64*)cntp, ranks,
                                                     x_s, x_t, xb_s, xb_t,
                                                     E, N, blkE, nd);
    scanAI_kernel<<<nTiles, 256, 0, stream>>>(cntp, dinv, tsum, total);
    scanB_kernel<<<1, 512, 0, stream>>>(tsum, toff, nTiles);
    scanC_kernel<<<nTiles, 256, 0, stream>>>(cntp, toff, start, total, 2 * E);

    slot_kernel<<<blkE, 256, 0, stream>>>(start, row, col, ew, ranks, dinv,
                                          ssst, es, et, E, N);

    // slot-range size per XCD, multiple of 8 slots (64B lines of int2)
    int SL = ((2 * E + NXCD - 1) / NXCD + 7) & ~7;
    fillX_kernel<<<NXCD * blkE, 256, 0, stream>>>(ssst, es, et, edges, E, SL);

    long long pull_threads = (long long)total * 64;
    int blkP = (int)((pull_threads + 255) / 256);
    pull1_kernel<<<blkP, 256, 0, stream>>>(start, (const int2*)edges, dinv, xb_s, xb_t,
                                           x_s, x_t, ab_s, ab_t, N);
    pull2_kernel<<<blkP, 256, 0, stream>>>(start, (const int2*)edges, dinv, ab_s, ab_t,
                                           x_s, x_t, out, w_s, w_t, N);
}

// Round 6
// 358.048 us; speedup vs baseline: 1.2705x; 1.0238x over previous
//
#include <hip/hip_runtime.h>

#define D 128
#define FILLV 0.5f
#define PAD 2    // u64 counter per bucket, contiguous. Layout does NOT matter
                 // for atomic cost (round-4 PMC: ~32B fabric write-through per
                 // device-scope atomic regardless of padding) — kept small for
                 // the cheap memset.
#define NXCD 8
#define EPT 8    // edges per thread in cnt: 16 independent atomics in flight
                 // (round-4 theory: atomic path is latency x MLP bound, not
                 // throughput bound — 2 in-flight/wave gave only ~22 G/s)

typedef unsigned short u16;
typedef unsigned long long u64;
typedef unsigned uv4 __attribute__((ext_vector_type(4)));  // native vec for
                                                           // nontemporal 16B

__device__ __forceinline__ u16 f2bf(float f) {          // RNE fp32 -> bf16
    unsigned u = __float_as_uint(f);
    u += 0x7FFF + ((u >> 16) & 1);
    return (u16)(u >> 16);
}
__device__ __forceinline__ float bf2f(u16 h) {
    return __uint_as_float(((unsigned)h) << 16);
}

// ---------------------------------------------------------------------------
// FUSED pass 1: edge blocks (first, so atomics start earliest) each handle
// EPT edges: vector-load (row,col,w), issue 2*EPT independent packed 64-bit
// atomics back-to-back (count in high word, w*2^24 fixed-point degree in low
// word; no carry for degree << 256), THEN consume the returns (within-bucket
// ranks, packed u16x2, stored as 16B vectors). Conversion blocks (after)
// stream the fp32->bf16 staging copies — pure-BW work hidden under atomic
// latency.
__global__ void cnt_tobf_kernel(const int* __restrict__ row, const int* __restrict__ col,
                                const float* __restrict__ w,
                                u64* __restrict__ cntp64, unsigned* __restrict__ ranks,
                                const float* __restrict__ x_s, const float* __restrict__ x_t,
                                u16* __restrict__ xb_s, u16* __restrict__ xb_t,
                                int E, int N, int nEB, long long nd) {
    if ((int)blockIdx.x < nEB) {
        long long g  = (long long)blockIdx.x * 256 + threadIdx.x;
        long long e0 = g * EPT;
        if (e0 >= E) return;
        if (e0 + EPT <= E && (E & 3) == 0) {
            int rr[EPT]; int cc[EPT]; unsigned fx[EPT];
            #pragma unroll
            for (int h = 0; h < EPT / 4; ++h) {
                int q = (int)(e0 >> 2) + h;
                int4   r4 = *(const int4*)(row + 4 * (size_t)q);
                int4   c4 = *(const int4*)(col + 4 * (size_t)q);
                float4 w4 = *(const float4*)(w + 4 * (size_t)q);
                rr[4*h] = r4.x; rr[4*h+1] = r4.y; rr[4*h+2] = r4.z; rr[4*h+3] = r4.w;
                cc[4*h] = c4.x; cc[4*h+1] = c4.y; cc[4*h+2] = c4.z; cc[4*h+3] = c4.w;
                fx[4*h]   = (unsigned)(w4.x * 16777216.0f);
                fx[4*h+1] = (unsigned)(w4.y * 16777216.0f);
                fx[4*h+2] = (unsigned)(w4.z * 16777216.0f);
                fx[4*h+3] = (unsigned)(w4.w * 16777216.0f);
            }
            u64 oc[EPT], orr[EPT];
            #pragma unroll
            for (int k = 0; k < EPT; ++k) {          // 16 RMWs issued, no waits
                u64 add = (1ull << 32) | fx[k];
                oc[k]  = atomicAdd(&cntp64[(size_t)cc[k]], add);
                orr[k] = atomicAdd(&cntp64[(size_t)N + rr[k]], add);
            }
            unsigned pk[EPT];
            #pragma unroll
            for (int k = 0; k < EPT; ++k)
                pk[k] = ((unsigned)(orr[k] >> 32) << 16) | ((unsigned)(oc[k] >> 32) & 0xffffu);
            uv4 pa = {pk[0], pk[1], pk[2], pk[3]};
            uv4 pb = {pk[4], pk[5], pk[6], pk[7]};
            __builtin_nontemporal_store(pa, (uv4*)(ranks + e0));
            __builtin_nontemporal_store(pb, (uv4*)(ranks + e0 + 4));
        } else {                                     // tail / unaligned fallback
            for (long long e = e0; e < E && e < e0 + EPT; ++e) {
                int r = row[e], c = col[e];
                unsigned fxs = (unsigned)(w[e] * 16777216.0f);
                u64 add = (1ull << 32) | fxs;
                u64 oc  = atomicAdd(&cntp64[(size_t)c], add);
                u64 orr = atomicAdd(&cntp64[(size_t)N + r], add);
                ranks[e] = ((unsigned)(orr >> 32) << 16) | ((unsigned)(oc >> 32) & 0xffffu);
            }
        }
    } else {
        long long t = (long long)(blockIdx.x - nEB) * 256 + threadIdx.x;
        long long q = nd / 4;
        const float* x; u16* xb; long long i;
        if (t < q) { x = x_s; xb = xb_s; i = t * 4; }
        else if (t < 2 * q) { x = x_t; xb = xb_t; i = (t - q) * 4; }
        else return;
        float4 v = *(const float4*)(x + i);
        ushort4 o;
        o.x = f2bf(v.x); o.y = f2bf(v.y); o.z = f2bf(v.z); o.w = f2bf(v.w);
        *(ushort4*)(xb + i) = o;
    }
}

// -------------------- fused invert + scan phase A ---------------------------
// Unpack packed counter: dinv[i] = 1/(deg+FILL); re-store plain count (read
// again by scanC); block-reduce counts into tsum.
__global__ void scanAI_kernel(int* __restrict__ cntp, float* __restrict__ dinv,
                              int* __restrict__ tsum, int total) {
    __shared__ int sh[256];
    int gid = blockIdx.x * 256 + threadIdx.x;
    int cnt = 0;
    if (gid < total) {
        u64 v = *(const u64*)&cntp[(size_t)gid * PAD];
        float deg = (float)(unsigned)(v & 0xffffffffu) * (1.0f / 16777216.0f);
        dinv[gid] = 1.0f / (deg + FILLV);
        cnt = (int)(v >> 32);
        cntp[(size_t)gid * PAD] = cnt;
    }
    sh[threadIdx.x] = cnt;
    __syncthreads();
    for (int off = 128; off > 0; off >>= 1) {
        if (threadIdx.x < off) sh[threadIdx.x] += sh[threadIdx.x + off];
        __syncthreads();
    }
    if (threadIdx.x == 0) tsum[blockIdx.x] = sh[0];
}

// scanC with scanB folded in: each block reduces its own tsum-prefix
// (<=2 loads/thread + tree reduce), then does the intra-block scan.
__global__ void scanC_kernel(const int* __restrict__ cntp, const int* __restrict__ tsum,
                             int* __restrict__ start, int total, int grand_total) {
    __shared__ int sh[256];
    int acc = 0;
    for (int j = threadIdx.x; j < (int)blockIdx.x; j += 256) acc += tsum[j];
    sh[threadIdx.x] = acc;
    __syncthreads();
    for (int off = 128; off > 0; off >>= 1) {
        if (threadIdx.x < off) sh[threadIdx.x] += sh[threadIdx.x + off];
        __syncthreads();
    }
    int bpref = sh[0];
    __syncthreads();
    int gid = blockIdx.x * 256 + threadIdx.x;
    int v = (gid < total) ? cntp[(size_t)gid * PAD] : 0;
    sh[threadIdx.x] = v;
    __syncthreads();
    for (int off = 1; off < 256; off <<= 1) {
        int u = 0;
        if (threadIdx.x >= off) u = sh[threadIdx.x - off];
        __syncthreads();
        sh[threadIdx.x] += u;
        __syncthreads();
    }
    int run = bpref + sh[threadIdx.x] - v;   // exclusive
    if (gid < total) start[gid] = run;
    if (gid == 0) start[total] = grand_total;
}

// Pass 2a (once, non-redundant, 4 edges/thread for gather MLP): do ALL
// per-edge gathers exactly once and emit coalesced record streams: packed
// slots (ss,st) and the two int2 payloads. slot = start[bucket] + rank.
__global__ void slot_kernel(const int* __restrict__ start,
                            const int* __restrict__ row, const int* __restrict__ col,
                            const float* __restrict__ w, const unsigned* __restrict__ ranks,
                            const float* __restrict__ dinv,
                            u64* __restrict__ ssst, u64* __restrict__ es, u64* __restrict__ et,
                            int E, int N) {
    long long g  = (long long)blockIdx.x * blockDim.x + threadIdx.x;
    long long e0 = g * 4;
    if (e0 >= E) return;
    if (e0 + 4 <= E && (E & 3) == 0) {
        int q = (int)(e0 >> 2);
        int4   r4 = *(const int4*)(row + 4 * (size_t)q);
        int4   c4 = *(const int4*)(col + 4 * (size_t)q);
        float4 w4 = *(const float4*)(w + 4 * (size_t)q);
        uv4    p4 = __builtin_nontemporal_load((const uv4*)(ranks + e0));
        int rr[4] = {r4.x, r4.y, r4.z, r4.w};
        int cc[4] = {c4.x, c4.y, c4.z, c4.w};
        float ww[4] = {w4.x, w4.y, w4.z, w4.w};
        unsigned pk[4] = {p4.x, p4.y, p4.z, p4.w};
        #pragma unroll
        for (int k = 0; k < 4; ++k) {
            int ss = start[cc[k]] + (int)(pk[k] & 0xffffu);
            int st = start[N + rr[k]] + (int)(pk[k] >> 16);
            float wns = ww[k] * dinv[N + rr[k]];
            float wnt = ww[k] * dinv[cc[k]];
            u64 sv = ((u64)(unsigned)st << 32) | (unsigned)ss;
            u64 ev = ((u64)__float_as_uint(wns) << 32) | (unsigned)rr[k];
            u64 tv = ((u64)__float_as_uint(wnt) << 32) | (unsigned)cc[k];
            __builtin_nontemporal_store(sv, ssst + e0 + k);
            __builtin_nontemporal_store(ev, es + e0 + k);
            __builtin_nontemporal_store(tv, et + e0 + k);
        }
    } else {
        for (long long e = e0; e < E && e < e0 + 4; ++e) {
            int r = row[e], c = col[e];
            float we = w[e];
            unsigned pk = ranks[e];
            int ss = start[c] + (int)(pk & 0xffffu);
            int st = start[N + r] + (int)(pk >> 16);
            float wns = we * dinv[N + r];
            float wnt = we * dinv[c];
            __builtin_nontemporal_store(((u64)(unsigned)st << 32) | (unsigned)ss, ssst + e);
            __builtin_nontemporal_store(((u64)__float_as_uint(wns) << 32) | (unsigned)r, es + e);
            __builtin_nontemporal_store(((u64)__float_as_uint(wnt) << 32) | (unsigned)c, et + e);
        }
    }
}

// Pass 2b: XCD-range-partitioned filter scatter. ZERO gathers, ZERO atomics —
// pure sequential nontemporal streaming of the precomputed records. Slot space
// [0,2E) split into NXCD contiguous 64B-aligned ranges; blocks with
// blockIdx&7 == rid land on XCD rid (round-robin dispatch) and write ONLY
// slots in their range -> the ~8 payloads sharing a 64B line merge in ONE
// XCD's L2. Payload loads are predicated; slots are a permutation of [0,2E),
// so each record is written by exactly one XCD.
__global__ void fillX_kernel(const u64* __restrict__ ssst,
                             const u64* __restrict__ es, const u64* __restrict__ et,
                             u64* __restrict__ edges, int E, int SL) {
    int e = (int)(blockIdx.x >> 3) * blockDim.x + threadIdx.x;
    int rid = blockIdx.x & 7;
    if (e >= E) return;
    int lo = rid * SL, hi = lo + SL;
    u64 sv = __builtin_nontemporal_load(ssst + e);
    int ss = (int)(unsigned)(sv & 0xffffffffu);
    int st = (int)(unsigned)(sv >> 32);
    bool ds = (ss >= lo) & (ss < hi);
    bool dt = (st >= lo) & (st < hi);
    if (ds) {
        u64 ev = __builtin_nontemporal_load(es + e);
        edges[ss] = ev;
    }
    if (dt) {
        u64 tv = __builtin_nontemporal_load(et + e);
        edges[st] = tv;
    }
}

// ---------------------------------------------------------------------------
// Pull kernels: wave per bucket; HALF-WAVE per edge (bf16 row = 256B = 32
// lanes x ushort4). Main loop: 8 edges/iter (4 per half, 4 gathers in flight);
// mid step 4; tail by half 0. Payload loads are wave-uniform -> s_load.
__global__ void pull1_kernel(const int* __restrict__ start, const int2* __restrict__ edges,
                             const float* __restrict__ dinv,
                             const u16* __restrict__ xb_s, const u16* __restrict__ xb_t,
                             const float* __restrict__ x_s, const float* __restrict__ x_t,
                             u16* __restrict__ ab_s, u16* __restrict__ ab_t, int N) {
    int wid0 = (int)(((long long)blockIdx.x * blockDim.x + threadIdx.x) >> 6);
    int wid = __builtin_amdgcn_readfirstlane(wid0);
    int lane = threadIdx.x & 63;
    int half = lane >> 5, hl = lane & 31;
    if (wid >= 2 * N) return;
    const u16* xb; const float* x; u16* ab; int i, o;
    if (wid < N) { i = wid;     o = N; xb = xb_s; x = x_s; ab = ab_s; }
    else         { i = wid - N; o = 0; xb = xb_t; x = x_t; ab = ab_t; }
    int s0 = start[wid], s1 = start[wid + 1];
    float a0 = 0.f, a1 = 0.f, a2 = 0.f, a3 = 0.f;
    int k = s0;
    for (; k + 8 <= s1; k += 8) {
        int b = k + 4 * half;
        int2 p0 = edges[b], p1 = edges[b + 1], p2 = edges[b + 2], p3 = edges[b + 3];
        ushort4 v0 = *(const ushort4*)(xb + (size_t)p0.x * D + hl * 4);
        ushort4 v1 = *(const ushort4*)(xb + (size_t)p1.x * D + hl * 4);
        ushort4 v2 = *(const ushort4*)(xb + (size_t)p2.x * D + hl * 4);
        ushort4 v3 = *(const ushort4*)(xb + (size_t)p3.x * D + hl * 4);
        float w0v = __int_as_float(p0.y), w1v = __int_as_float(p1.y);
        float w2v = __int_as_float(p2.y), w3v = __int_as_float(p3.y);
        a0 += w0v * bf2f(v0.x) + w1v * bf2f(v1.x) + w2v * bf2f(v2.x) + w3v * bf2f(v3.x);
        a1 += w0v * bf2f(v0.y) + w1v * bf2f(v1.y) + w2v * bf2f(v2.y) + w3v * bf2f(v3.y);
        a2 += w0v * bf2f(v0.z) + w1v * bf2f(v1.z) + w2v * bf2f(v2.z) + w3v * bf2f(v3.z);
        a3 += w0v * bf2f(v0.w) + w1v * bf2f(v1.w) + w2v * bf2f(v2.w) + w3v * bf2f(v3.w);
    }
    if (k + 4 <= s1) {
        int b = k + 2 * half;
        int2 p0 = edges[b], p1 = edges[b + 1];
        ushort4 v0 = *(const ushort4*)(xb + (size_t)p0.x * D + hl * 4);
        ushort4 v1 = *(const ushort4*)(xb + (size_t)p1.x * D + hl * 4);
        float w0v = __int_as_float(p0.y), w1v = __int_as_float(p1.y);
        a0 += w0v * bf2f(v0.x) + w1v * bf2f(v1.x);
        a1 += w0v * bf2f(v0.y) + w1v * bf2f(v1.y);
        a2 += w0v * bf2f(v0.z) + w1v * bf2f(v1.z);
        a3 += w0v * bf2f(v0.w) + w1v * bf2f(v1.w);
        k += 4;
    }
    for (; k < s1; ++k) {
        if (half == 0) {
            int2 p = edges[k];
            ushort4 v = *(const ushort4*)(xb + (size_t)p.x * D + hl * 4);
            float wv = __int_as_float(p.y);
            a0 += wv * bf2f(v.x); a1 += wv * bf2f(v.y);
            a2 += wv * bf2f(v.z); a3 += wv * bf2f(v.w);
        }
    }
    a0 += __shfl_xor(a0, 32); a1 += __shfl_xor(a1, 32);
    a2 += __shfl_xor(a2, 32); a3 += __shfl_xor(a3, 32);
    if (half == 0) {
        float sw = FILLV * dinv[o + i];
        float4 xv = *(const float4*)(x + (size_t)i * D + hl * 4);
        a0 += sw * xv.x; a1 += sw * xv.y; a2 += sw * xv.z; a3 += sw * xv.w;
        ushort4 ov;
        ov.x = f2bf(a0); ov.y = f2bf(a1); ov.z = f2bf(a2); ov.w = f2bf(a3);
        *(ushort4*)(ab + (size_t)i * D + hl * 4) = ov;
    }
}

// Hop-2 pull + fused epilogue: out_half = w0*x + w1*a + w2*(conv(a)).
__global__ void pull2_kernel(const int* __restrict__ start, const int2* __restrict__ edges,
                             const float* __restrict__ dinv,
                             const u16* __restrict__ ab_s, const u16* __restrict__ ab_t,
                             const float* __restrict__ x_s, const float* __restrict__ x_t,
                             float* __restrict__ out,
                             const float* __restrict__ w_s, const float* __restrict__ w_t, int N) {
    int wid0 = (int)(((long long)blockIdx.x * blockDim.x + threadIdx.x) >> 6);
    int wid = __builtin_amdgcn_readfirstlane(wid0);
    int lane = threadIdx.x & 63;
    int half = lane >> 5, hl = lane & 31;
    if (wid >= 2 * N) return;
    const u16* ab; const float* x; const float* wv3; int i, o, hoff;
    if (wid < N) { i = wid;     o = N; ab = ab_s; x = x_s; wv3 = w_s; hoff = 0; }
    else         { i = wid - N; o = 0; ab = ab_t; x = x_t; wv3 = w_t; hoff = D; }
    int s0 = start[wid], s1 = start[wid + 1];
    float a0 = 0.f, a1 = 0.f, a2 = 0.f, a3 = 0.f;
    int k = s0;
    for (; k + 8 <= s1; k += 8) {
        int b = k + 4 * half;
        int2 p0 = edges[b], p1 = edges[b + 1], p2 = edges[b + 2], p3 = edges[b + 3];
        ushort4 v0 = *(const ushort4*)(ab + (size_t)p0.x * D + hl * 4);
        ushort4 v1 = *(const ushort4*)(ab + (size_t)p1.x * D + hl * 4);
        ushort4 v2 = *(const ushort4*)(ab + (size_t)p2.x * D + hl * 4);
        ushort4 v3 = *(const ushort4*)(ab + (size_t)p3.x * D + hl * 4);
        float w0v = __int_as_float(p0.y), w1v = __int_as_float(p1.y);
        float w2v = __int_as_float(p2.y), w3v = __int_as_float(p3.y);
        a0 += w0v * bf2f(v0.x) + w1v * bf2f(v1.x) + w2v * bf2f(v2.x) + w3v * bf2f(v3.x);
        a1 += w0v * bf2f(v0.y) + w1v * bf2f(v1.y) + w2v * bf2f(v2.y) + w3v * bf2f(v3.y);
        a2 += w0v * bf2f(v0.z) + w1v * bf2f(v1.z) + w2v * bf2f(v2.z) + w3v * bf2f(v3.z);
        a3 += w0v * bf2f(v0.w) + w1v * bf2f(v1.w) + w2v * bf2f(v2.w) + w3v * bf2f(v3.w);
    }
    if (k + 4 <= s1) {
        int b = k + 2 * half;
        int2 p0 = edges[b], p1 = edges[b + 1];
        ushort4 v0 = *(const ushort4*)(ab + (size_t)p0.x * D + hl * 4);
        ushort4 v1 = *(const ushort4*)(ab + (size_t)p1.x * D + hl * 4);
        float w0v = __int_as_float(p0.y), w1v = __int_as_float(p1.y);
        a0 += w0v * bf2f(v0.x) + w1v * bf2f(v1.x);
        a1 += w0v * bf2f(v0.y) + w1v * bf2f(v1.y);
        a2 += w0v * bf2f(v0.z) + w1v * bf2f(v1.z);
        a3 += w0v * bf2f(v0.w) + w1v * bf2f(v1.w);
        k += 4;
    }
    for (; k < s1; ++k) {
        if (half == 0) {
            int2 p = edges[k];
            ushort4 v = *(const ushort4*)(ab + (size_t)p.x * D + hl * 4);
            float wv = __int_as_float(p.y);
            a0 += wv * bf2f(v.x); a1 += wv * bf2f(v.y);
            a2 += wv * bf2f(v.z); a3 += wv * bf2f(v.w);
        }
    }
    a0 += __shfl_xor(a0, 32); a1 += __shfl_xor(a1, 32);
    a2 += __shfl_xor(a2, 32); a3 += __shfl_xor(a3, 32);
    if (half == 0) {
        float sw = FILLV * dinv[o + i];
        ushort4 av = *(const ushort4*)(ab + (size_t)i * D + hl * 4);
        float b0 = bf2f(av.x), b1 = bf2f(av.y), b2 = bf2f(av.z), b3 = bf2f(av.w);
        a0 += sw * b0; a1 += sw * b1; a2 += sw * b2; a3 += sw * b3;
        float w0 = wv3[0], w1 = wv3[1], w2 = wv3[2];
        float4 xv = *(const float4*)(x + (size_t)i * D + hl * 4);
        float4 ov;
        ov.x = w0 * xv.x + w1 * b0 + w2 * a0;
        ov.y = w0 * xv.y + w1 * b1 + w2 * a1;
        ov.z = w0 * xv.z + w1 * b2 + w2 * a2;
        ov.w = w0 * xv.w + w1 * b3 + w2 * a3;
        *(float4*)(out + (size_t)i * 2 * D + hoff + hl * 4) = ov;
    }
}

// ---------------------------------------------------------------------------
extern "C" void kernel_launch(void* const* d_in, const int* in_sizes, int n_in,
                              void* d_out, int out_size, void* d_ws, size_t ws_size,
                              hipStream_t stream) {
    const float* x_s = (const float*)d_in[0];
    const float* x_t = (const float*)d_in[1];
    const int*   ei  = (const int*)d_in[2];
    const float* ew  = (const float*)d_in[3];
    const float* w_s = (const float*)d_in[4];
    const float* w_t = (const float*)d_in[5];
    const int N = in_sizes[0] / D;
    const int E = in_sizes[3];
    const int* row = ei;
    const int* col = ei + E;

    const int total = 2 * N;
    const int nTiles = (total + 255) / 256;

    // Workspace (d_ws): [dinv 2N][start 2N+2][tsum 512][align]
    // [edges 2E int2 (64B-aligned)] [xb_s ND u16][xb_t ND u16][ab_s][ab_t]
    // Packed cntp (2N*PAD ints = 800KB) aliases ab_s: dead before pull1.
    float* f      = (float*)d_ws;
    float* dinv   = f;                              // 2N
    int*   start  = (int*)(f + (size_t)total);      // 2N+2
    int*   tsum   = start + (total + 2);            // 512
    char*  pc     = (char*)(tsum + 512);
    pc = (char*)(((size_t)pc + 255) & ~(size_t)255);
    u64*   edges  = (u64*)pc;                       // 2E int2, 64B-aligned
    u16*   xb_s   = (u16*)(edges + 2 * (size_t)E);
    u16*   xb_t   = xb_s + (size_t)N * D;
    u16*   ab_s   = xb_t + (size_t)N * D;
    u16*   ab_t   = ab_s + (size_t)N * D;
    int*   cntp   = (int*)ab_s;                     // alias, dead before pull1

    // d_out scratch (dead until pull2 writes): ranks[E] u32, then the three
    // record streams ssst/es/et (u64[E] each), 16B-aligned. Total ~28E bytes.
    unsigned* ranks = (unsigned*)d_out;
    char* po = (char*)d_out + (((size_t)E * 4 + 15) & ~(size_t)15);
    u64* ssst = (u64*)po;
    u64* es   = ssst + (size_t)E;
    u64* et   = es + (size_t)E;
    float* out = (float*)d_out;

    hipMemsetAsync(cntp, 0, (size_t)total * PAD * sizeof(int), stream);

    long long nd = (long long)N * D;
    int blkC = (int)((nd / 2 + 255) / 256);
    int blkE = (E + 255) / 256;
    int nEB  = (E + EPT * 256 - 1) / (EPT * 256);
    cnt_tobf_kernel<<<nEB + blkC, 256, 0, stream>>>(row, col, ew, (u64*)cntp, ranks,
                                                    x_s, x_t, xb_s, xb_t,
                                                    E, N, nEB, nd);
    scanAI_kernel<<<nTiles, 256, 0, stream>>>(cntp, dinv, tsum, total);
    scanC_kernel<<<nTiles, 256, 0, stream>>>(cntp, tsum, start, total, 2 * E);

    int blkS = (E / 4 + 256) / 256 + 1;
    slot_kernel<<<blkS, 256, 0, stream>>>(start, row, col, ew, ranks, dinv,
                                          ssst, es, et, E, N);

    // slot-range size per XCD, multiple of 8 slots (64B lines of int2)
    int SL = ((2 * E + NXCD - 1) / NXCD + 7) & ~7;
    fillX_kernel<<<NXCD * blkE, 256, 0, stream>>>(ssst, es, et, edges, E, SL);

    long long pull_threads = (long long)total * 64;
    int blkP = (int)((pull_threads + 255) / 256);
    pull1_kernel<<<blkP, 256, 0, stream>>>(start, (const int2*)edges, dinv, xb_s, xb_t,
                                           x_s, x_t, ab_s, ab_t, N);
    pull2_kernel<<<blkP, 256, 0, stream>>>(start, (const int2*)edges, dinv, ab_s, ab_t,
                                           x_s, x_t, out, w_s, w_t, N);
}

// Round 7
// 351.819 us; speedup vs baseline: 1.2930x; 1.0177x over previous
//
#include <hip/hip_runtime.h>

#define D 128
#define FILLV 0.5f
#define NXCD 8
#define EPT 8    // edges per thread in cnt (kept from r6; MLP is not the limit
                 // but batching also amortizes index loads)

// Packed u32 bucket counter: count in bits[22:31] (max bucket count ~45 << 1023),
// degree as w*2^16 fixed-point in bits[0:21] (sum < 45*2^16 < 2^22, no carry).
// r6 evidence: atomic path is throughput-bound at the device-scope RMW point
// (~20 G/s, MLP- and layout-insensitive, ~32B write-through per u64 RMW).
// This round's experiment: halve the RMW width -> distinguishes per-op vs
// per-byte bound at the coherence point.
#define CNT_SHIFT 22
#define DEG_MASK  0x3FFFFFu

typedef unsigned short u16;
typedef unsigned long long u64;
typedef unsigned uv4 __attribute__((ext_vector_type(4)));  // native vec for
                                                           // nontemporal 16B

__device__ __forceinline__ u16 f2bf(float f) {          // RNE fp32 -> bf16
    unsigned u = __float_as_uint(f);
    u += 0x7FFF + ((u >> 16) & 1);
    return (u16)(u >> 16);
}
__device__ __forceinline__ float bf2f(u16 h) {
    return __uint_as_float(((unsigned)h) << 16);
}

// ---------------------------------------------------------------------------
// FUSED pass 1: edge blocks (first, so atomics start earliest) each handle
// EPT edges: vector-load (row,col,w), issue 2*EPT independent packed u32
// atomics back-to-back, THEN consume the returns (within-bucket ranks, packed
// u16x2, stored as 16B vectors). Conversion blocks (after) stream the
// fp32->bf16 staging copies — pure-BW work hidden under atomic latency.
__global__ void cnt_tobf_kernel(const int* __restrict__ row, const int* __restrict__ col,
                                const float* __restrict__ w,
                                unsigned* __restrict__ cnt32, unsigned* __restrict__ ranks,
                                const float* __restrict__ x_s, const float* __restrict__ x_t,
                                u16* __restrict__ xb_s, u16* __restrict__ xb_t,
                                int E, int N, int nEB, long long nd) {
    if ((int)blockIdx.x < nEB) {
        long long g  = (long long)blockIdx.x * 256 + threadIdx.x;
        long long e0 = g * EPT;
        if (e0 >= E) return;
        if (e0 + EPT <= E && (E & 3) == 0) {
            int rr[EPT]; int cc[EPT]; unsigned fx[EPT];
            #pragma unroll
            for (int h = 0; h < EPT / 4; ++h) {
                int q = (int)(e0 >> 2) + h;
                int4   r4 = *(const int4*)(row + 4 * (size_t)q);
                int4   c4 = *(const int4*)(col + 4 * (size_t)q);
                float4 w4 = *(const float4*)(w + 4 * (size_t)q);
                rr[4*h] = r4.x; rr[4*h+1] = r4.y; rr[4*h+2] = r4.z; rr[4*h+3] = r4.w;
                cc[4*h] = c4.x; cc[4*h+1] = c4.y; cc[4*h+2] = c4.z; cc[4*h+3] = c4.w;
                fx[4*h]   = (unsigned)(w4.x * 65536.0f);
                fx[4*h+1] = (unsigned)(w4.y * 65536.0f);
                fx[4*h+2] = (unsigned)(w4.z * 65536.0f);
                fx[4*h+3] = (unsigned)(w4.w * 65536.0f);
            }
            unsigned oc[EPT], orr[EPT];
            #pragma unroll
            for (int k = 0; k < EPT; ++k) {          // 16 RMWs issued, no waits
                unsigned add = (1u << CNT_SHIFT) | fx[k];
                oc[k]  = atomicAdd(&cnt32[(size_t)cc[k]], add);
                orr[k] = atomicAdd(&cnt32[(size_t)N + rr[k]], add);
            }
            unsigned pk[EPT];
            #pragma unroll
            for (int k = 0; k < EPT; ++k)
                pk[k] = ((orr[k] >> CNT_SHIFT) << 16) | (oc[k] >> CNT_SHIFT);
            uv4 pa = {pk[0], pk[1], pk[2], pk[3]};
            uv4 pb = {pk[4], pk[5], pk[6], pk[7]};
            __builtin_nontemporal_store(pa, (uv4*)(ranks + e0));
            __builtin_nontemporal_store(pb, (uv4*)(ranks + e0 + 4));
        } else {                                     // tail / unaligned fallback
            for (long long e = e0; e < E && e < e0 + EPT; ++e) {
                int r = row[e], c = col[e];
                unsigned add = (1u << CNT_SHIFT) | (unsigned)(w[e] * 65536.0f);
                unsigned oc  = atomicAdd(&cnt32[(size_t)c], add);
                unsigned orr = atomicAdd(&cnt32[(size_t)N + r], add);
                ranks[e] = ((orr >> CNT_SHIFT) << 16) | (oc >> CNT_SHIFT);
            }
        }
    } else {
        long long t = (long long)(blockIdx.x - nEB) * 256 + threadIdx.x;
        long long q = nd / 4;
        const float* x; u16* xb; long long i;
        if (t < q) { x = x_s; xb = xb_s; i = t * 4; }
        else if (t < 2 * q) { x = x_t; xb = xb_t; i = (t - q) * 4; }
        else return;
        float4 v = *(const float4*)(x + i);
        ushort4 o;
        o.x = f2bf(v.x); o.y = f2bf(v.y); o.z = f2bf(v.z); o.w = f2bf(v.w);
        *(ushort4*)(xb + i) = o;
    }
}

// -------------------- fused invert + scan phase A ---------------------------
// Unpack packed u32 counter: dinv[i] = 1/(deg+FILL); re-store plain count
// (read again by scanC); block-reduce counts into tsum.
__global__ void scanAI_kernel(unsigned* __restrict__ cnt32, float* __restrict__ dinv,
                              int* __restrict__ tsum, int total) {
    __shared__ int sh[256];
    int gid = blockIdx.x * 256 + threadIdx.x;
    int cnt = 0;
    if (gid < total) {
        unsigned v = cnt32[gid];
        float deg = (float)(v & DEG_MASK) * (1.0f / 65536.0f);
        dinv[gid] = 1.0f / (deg + FILLV);
        cnt = (int)(v >> CNT_SHIFT);
        cnt32[gid] = (unsigned)cnt;
    }
    sh[threadIdx.x] = cnt;
    __syncthreads();
    for (int off = 128; off > 0; off >>= 1) {
        if (threadIdx.x < off) sh[threadIdx.x] += sh[threadIdx.x + off];
        __syncthreads();
    }
    if (threadIdx.x == 0) tsum[blockIdx.x] = sh[0];
}

// scanC with scanB folded in: each block reduces its own tsum-prefix
// (<=2 loads/thread + tree reduce), then does the intra-block scan.
__global__ void scanC_kernel(const unsigned* __restrict__ cnt32, const int* __restrict__ tsum,
                             int* __restrict__ start, int total, int grand_total) {
    __shared__ int sh[256];
    int acc = 0;
    for (int j = threadIdx.x; j < (int)blockIdx.x; j += 256) acc += tsum[j];
    sh[threadIdx.x] = acc;
    __syncthreads();
    for (int off = 128; off > 0; off >>= 1) {
        if (threadIdx.x < off) sh[threadIdx.x] += sh[threadIdx.x + off];
        __syncthreads();
    }
    int bpref = sh[0];
    __syncthreads();
    int gid = blockIdx.x * 256 + threadIdx.x;
    int v = (gid < total) ? (int)cnt32[gid] : 0;
    sh[threadIdx.x] = v;
    __syncthreads();
    for (int off = 1; off < 256; off <<= 1) {
        int u = 0;
        if (threadIdx.x >= off) u = sh[threadIdx.x - off];
        __syncthreads();
        sh[threadIdx.x] += u;
        __syncthreads();
    }
    int run = bpref + sh[threadIdx.x] - v;   // exclusive
    if (gid < total) start[gid] = run;
    if (gid == 0) start[total] = grand_total;
}

// Pass 2a (once, non-redundant, 4 edges/thread for gather MLP): do ALL
// per-edge gathers exactly once and emit coalesced record streams: packed
// slots (ss,st) and the two int2 payloads. slot = start[bucket] + rank.
__global__ void slot_kernel(const int* __restrict__ start,
                            const int* __restrict__ row, const int* __restrict__ col,
                            const float* __restrict__ w, const unsigned* __restrict__ ranks,
                            const float* __restrict__ dinv,
                            u64* __restrict__ ssst, u64* __restrict__ es, u64* __restrict__ et,
                            int E, int N) {
    long long g  = (long long)blockIdx.x * blockDim.x + threadIdx.x;
    long long e0 = g * 4;
    if (e0 >= E) return;
    if (e0 + 4 <= E && (E & 3) == 0) {
        int q = (int)(e0 >> 2);
        int4   r4 = *(const int4*)(row + 4 * (size_t)q);
        int4   c4 = *(const int4*)(col + 4 * (size_t)q);
        float4 w4 = *(const float4*)(w + 4 * (size_t)q);
        uv4    p4 = __builtin_nontemporal_load((const uv4*)(ranks + e0));
        int rr[4] = {r4.x, r4.y, r4.z, r4.w};
        int cc[4] = {c4.x, c4.y, c4.z, c4.w};
        float ww[4] = {w4.x, w4.y, w4.z, w4.w};
        unsigned pk[4] = {p4.x, p4.y, p4.z, p4.w};
        #pragma unroll
        for (int k = 0; k < 4; ++k) {
            int ss = start[cc[k]] + (int)(pk[k] & 0xffffu);
            int st = start[N + rr[k]] + (int)(pk[k] >> 16);
            float wns = ww[k] * dinv[N + rr[k]];
            float wnt = ww[k] * dinv[cc[k]];
            u64 sv = ((u64)(unsigned)st << 32) | (unsigned)ss;
            u64 ev = ((u64)__float_as_uint(wns) << 32) | (unsigned)rr[k];
            u64 tv = ((u64)__float_as_uint(wnt) << 32) | (unsigned)cc[k];
            __builtin_nontemporal_store(sv, ssst + e0 + k);
            __builtin_nontemporal_store(ev, es + e0 + k);
            __builtin_nontemporal_store(tv, et + e0 + k);
        }
    } else {
        for (long long e = e0; e < E && e < e0 + 4; ++e) {
            int r = row[e], c = col[e];
            float we = w[e];
            unsigned pk = ranks[e];
            int ss = start[c] + (int)(pk & 0xffffu);
            int st = start[N + r] + (int)(pk >> 16);
            float wns = we * dinv[N + r];
            float wnt = we * dinv[c];
            __builtin_nontemporal_store(((u64)(unsigned)st << 32) | (unsigned)ss, ssst + e);
            __builtin_nontemporal_store(((u64)__float_as_uint(wns) << 32) | (unsigned)r, es + e);
            __builtin_nontemporal_store(((u64)__float_as_uint(wnt) << 32) | (unsigned)c, et + e);
        }
    }
}

// Pass 2b: XCD-range-partitioned filter scatter. ZERO gathers, ZERO atomics —
// pure sequential nontemporal streaming of the precomputed records. Slot space
// [0,2E) split into NXCD contiguous 64B-aligned ranges; blocks with
// blockIdx&7 == rid land on XCD rid (round-robin dispatch) and write ONLY
// slots in their range -> the ~8 payloads sharing a 64B line merge in ONE
// XCD's L2. Payload loads are predicated; slots are a permutation of [0,2E),
// so each record is written by exactly one XCD.
__global__ void fillX_kernel(const u64* __restrict__ ssst,
                             const u64* __restrict__ es, const u64* __restrict__ et,
                             u64* __restrict__ edges, int E, int SL) {
    int e = (int)(blockIdx.x >> 3) * blockDim.x + threadIdx.x;
    int rid = blockIdx.x & 7;
    if (e >= E) return;
    int lo = rid * SL, hi = lo + SL;
    u64 sv = __builtin_nontemporal_load(ssst + e);
    int ss = (int)(unsigned)(sv & 0xffffffffu);
    int st = (int)(unsigned)(sv >> 32);
    bool ds = (ss >= lo) & (ss < hi);
    bool dt = (st >= lo) & (st < hi);
    if (ds) {
        u64 ev = __builtin_nontemporal_load(es + e);
        edges[ss] = ev;
    }
    if (dt) {
        u64 tv = __builtin_nontemporal_load(et + e);
        edges[st] = tv;
    }
}

// ---------------------------------------------------------------------------
// Pull kernels: wave per bucket; HALF-WAVE per edge (bf16 row = 256B = 32
// lanes x ushort4). Main loop: 8 edges/iter (4 per half, 4 gathers in flight);
// mid step 4; tail by half 0. Payload loads are wave-uniform -> s_load.
__global__ void pull1_kernel(const int* __restrict__ start, const int2* __restrict__ edges,
                             const float* __restrict__ dinv,
                             const u16* __restrict__ xb_s, const u16* __restrict__ xb_t,
                             const float* __restrict__ x_s, const float* __restrict__ x_t,
                             u16* __restrict__ ab_s, u16* __restrict__ ab_t, int N) {
    int wid0 = (int)(((long long)blockIdx.x * blockDim.x + threadIdx.x) >> 6);
    int wid = __builtin_amdgcn_readfirstlane(wid0);
    int lane = threadIdx.x & 63;
    int half = lane >> 5, hl = lane & 31;
    if (wid >= 2 * N) return;
    const u16* xb; const float* x; u16* ab; int i, o;
    if (wid < N) { i = wid;     o = N; xb = xb_s; x = x_s; ab = ab_s; }
    else         { i = wid - N; o = 0; xb = xb_t; x = x_t; ab = ab_t; }
    int s0 = start[wid], s1 = start[wid + 1];
    float a0 = 0.f, a1 = 0.f, a2 = 0.f, a3 = 0.f;
    int k = s0;
    for (; k + 8 <= s1; k += 8) {
        int b = k + 4 * half;
        int2 p0 = edges[b], p1 = edges[b + 1], p2 = edges[b + 2], p3 = edges[b + 3];
        ushort4 v0 = *(const ushort4*)(xb + (size_t)p0.x * D + hl * 4);
        ushort4 v1 = *(const ushort4*)(xb + (size_t)p1.x * D + hl * 4);
        ushort4 v2 = *(const ushort4*)(xb + (size_t)p2.x * D + hl * 4);
        ushort4 v3 = *(const ushort4*)(xb + (size_t)p3.x * D + hl * 4);
        float w0v = __int_as_float(p0.y), w1v = __int_as_float(p1.y);
        float w2v = __int_as_float(p2.y), w3v = __int_as_float(p3.y);
        a0 += w0v * bf2f(v0.x) + w1v * bf2f(v1.x) + w2v * bf2f(v2.x) + w3v * bf2f(v3.x);
        a1 += w0v * bf2f(v0.y) + w1v * bf2f(v1.y) + w2v * bf2f(v2.y) + w3v * bf2f(v3.y);
        a2 += w0v * bf2f(v0.z) + w1v * bf2f(v1.z) + w2v * bf2f(v2.z) + w3v * bf2f(v3.z);
        a3 += w0v * bf2f(v0.w) + w1v * bf2f(v1.w) + w2v * bf2f(v2.w) + w3v * bf2f(v3.w);
    }
    if (k + 4 <= s1) {
        int b = k + 2 * half;
        int2 p0 = edges[b], p1 = edges[b + 1];
        ushort4 v0 = *(const ushort4*)(xb + (size_t)p0.x * D + hl * 4);
        ushort4 v1 = *(const ushort4*)(xb + (size_t)p1.x * D + hl * 4);
        float w0v = __int_as_float(p0.y), w1v = __int_as_float(p1.y);
        a0 += w0v * bf2f(v0.x) + w1v * bf2f(v1.x);
        a1 += w0v * bf2f(v0.y) + w1v * bf2f(v1.y);
        a2 += w0v * bf2f(v0.z) + w1v * bf2f(v1.z);
        a3 += w0v * bf2f(v0.w) + w1v * bf2f(v1.w);
        k += 4;
    }
    for (; k < s1; ++k) {
        if (half == 0) {
            int2 p = edges[k];
            ushort4 v = *(const ushort4*)(xb + (size_t)p.x * D + hl * 4);
            float wv = __int_as_float(p.y);
            a0 += wv * bf2f(v.x); a1 += wv * bf2f(v.y);
            a2 += wv * bf2f(v.z); a3 += wv * bf2f(v.w);
        }
    }
    a0 += __shfl_xor(a0, 32); a1 += __shfl_xor(a1, 32);
    a2 += __shfl_xor(a2, 32); a3 += __shfl_xor(a3, 32);
    if (half == 0) {
        float sw = FILLV * dinv[o + i];
        float4 xv = *(const float4*)(x + (size_t)i * D + hl * 4);
        a0 += sw * xv.x; a1 += sw * xv.y; a2 += sw * xv.z; a3 += sw * xv.w;
        ushort4 ov;
        ov.x = f2bf(a0); ov.y = f2bf(a1); ov.z = f2bf(a2); ov.w = f2bf(a3);
        *(ushort4*)(ab + (size_t)i * D + hl * 4) = ov;
    }
}

// Hop-2 pull + fused epilogue: out_half = w0*x + w1*a + w2*(conv(a)).
__global__ void pull2_kernel(const int* __restrict__ start, const int2* __restrict__ edges,
                             const float* __restrict__ dinv,
                             const u16* __restrict__ ab_s, const u16* __restrict__ ab_t,
                             const float* __restrict__ x_s, const float* __restrict__ x_t,
                             float* __restrict__ out,
                             const float* __restrict__ w_s, const float* __restrict__ w_t, int N) {
    int wid0 = (int)(((long long)blockIdx.x * blockDim.x + threadIdx.x) >> 6);
    int wid = __builtin_amdgcn_readfirstlane(wid0);
    int lane = threadIdx.x & 63;
    int half = lane >> 5, hl = lane & 31;
    if (wid >= 2 * N) return;
    const u16* ab; const float* x; const float* wv3; int i, o, hoff;
    if (wid < N) { i = wid;     o = N; ab = ab_s; x = x_s; wv3 = w_s; hoff = 0; }
    else         { i = wid - N; o = 0; ab = ab_t; x = x_t; wv3 = w_t; hoff = D; }
    int s0 = start[wid], s1 = start[wid + 1];
    float a0 = 0.f, a1 = 0.f, a2 = 0.f, a3 = 0.f;
    int k = s0;
    for (; k + 8 <= s1; k += 8) {
        int b = k + 4 * half;
        int2 p0 = edges[b], p1 = edges[b + 1], p2 = edges[b + 2], p3 = edges[b + 3];
        ushort4 v0 = *(const ushort4*)(ab + (size_t)p0.x * D + hl * 4);
        ushort4 v1 = *(const ushort4*)(ab + (size_t)p1.x * D + hl * 4);
        ushort4 v2 = *(const ushort4*)(ab + (size_t)p2.x * D + hl * 4);
        ushort4 v3 = *(const ushort4*)(ab + (size_t)p3.x * D + hl * 4);
        float w0v = __int_as_float(p0.y), w1v = __int_as_float(p1.y);
        float w2v = __int_as_float(p2.y), w3v = __int_as_float(p3.y);
        a0 += w0v * bf2f(v0.x) + w1v * bf2f(v1.x) + w2v * bf2f(v2.x) + w3v * bf2f(v3.x);
        a1 += w0v * bf2f(v0.y) + w1v * bf2f(v1.y) + w2v * bf2f(v2.y) + w3v * bf2f(v3.y);
        a2 += w0v * bf2f(v0.z) + w1v * bf2f(v1.z) + w2v * bf2f(v2.z) + w3v * bf2f(v3.z);
        a3 += w0v * bf2f(v0.w) + w1v * bf2f(v1.w) + w2v * bf2f(v2.w) + w3v * bf2f(v3.w);
    }
    if (k + 4 <= s1) {
        int b = k + 2 * half;
        int2 p0 = edges[b], p1 = edges[b + 1];
        ushort4 v0 = *(const ushort4*)(ab + (size_t)p0.x * D + hl * 4);
        ushort4 v1 = *(const ushort4*)(ab + (size_t)p1.x * D + hl * 4);
        float w0v = __int_as_float(p0.y), w1v = __int_as_float(p1.y);
        a0 += w0v * bf2f(v0.x) + w1v * bf2f(v1.x);
        a1 += w0v * bf2f(v0.y) + w1v * bf2f(v1.y);
        a2 += w0v * bf2f(v0.z) + w1v * bf2f(v1.z);
        a3 += w0v * bf2f(v0.w) + w1v * bf2f(v1.w);
        k += 4;
    }
    for (; k < s1; ++k) {
        if (half == 0) {
            int2 p = edges[k];
            ushort4 v = *(const ushort4*)(ab + (size_t)p.x * D + hl * 4);
            float wv = __int_as_float(p.y);
            a0 += wv * bf2f(v.x); a1 += wv * bf2f(v.y);
            a2 += wv * bf2f(v.z); a3 += wv * bf2f(v.w);
        }
    }
    a0 += __shfl_xor(a0, 32); a1 += __shfl_xor(a1, 32);
    a2 += __shfl_xor(a2, 32); a3 += __shfl_xor(a3, 32);
    if (half == 0) {
        float sw = FILLV * dinv[o + i];
        ushort4 av = *(const ushort4*)(ab + (size_t)i * D + hl * 4);
        float b0 = bf2f(av.x), b1 = bf2f(av.y), b2 = bf2f(av.z), b3 = bf2f(av.w);
        a0 += sw * b0; a1 += sw * b1; a2 += sw * b2; a3 += sw * b3;
        float w0 = wv3[0], w1 = wv3[1], w2 = wv3[2];
        float4 xv = *(const float4*)(x + (size_t)i * D + hl * 4);
        float4 ov;
        ov.x = w0 * xv.x + w1 * b0 + w2 * a0;
        ov.y = w0 * xv.y + w1 * b1 + w2 * a1;
        ov.z = w0 * xv.z + w1 * b2 + w2 * a2;
        ov.w = w0 * xv.w + w1 * b3 + w2 * a3;
        *(float4*)(out + (size_t)i * 2 * D + hoff + hl * 4) = ov;
    }
}

// ---------------------------------------------------------------------------
extern "C" void kernel_launch(void* const* d_in, const int* in_sizes, int n_in,
                              void* d_out, int out_size, void* d_ws, size_t ws_size,
                              hipStream_t stream) {
    const float* x_s = (const float*)d_in[0];
    const float* x_t = (const float*)d_in[1];
    const int*   ei  = (const int*)d_in[2];
    const float* ew  = (const float*)d_in[3];
    const float* w_s = (const float*)d_in[4];
    const float* w_t = (const float*)d_in[5];
    const int N = in_sizes[0] / D;
    const int E = in_sizes[3];
    const int* row = ei;
    const int* col = ei + E;

    const int total = 2 * N;
    const int nTiles = (total + 255) / 256;

    // Workspace (d_ws): [dinv 2N][start 2N+2][tsum 512][align]
    // [edges 2E int2 (64B-aligned)] [xb_s ND u16][xb_t ND u16][ab_s][ab_t]
    // Packed cnt32 (2N u32 = 400KB) aliases ab_s: dead before pull1.
    float* f      = (float*)d_ws;
    float* dinv   = f;                              // 2N
    int*   start  = (int*)(f + (size_t)total);      // 2N+2
    int*   tsum   = start + (total + 2);            // 512
    char*  pc     = (char*)(tsum + 512);
    pc = (char*)(((size_t)pc + 255) & ~(size_t)255);
    u64*   edges  = (u64*)pc;                       // 2E int2, 64B-aligned
    u16*   xb_s   = (u16*)(edges + 2 * (size_t)E);
    u16*   xb_t   = xb_s + (size_t)N * D;
    u16*   ab_s   = xb_t + (size_t)N * D;
    u16*   ab_t   = ab_s + (size_t)N * D;
    unsigned* cnt32 = (unsigned*)ab_s;              // alias, dead before pull1

    // d_out scratch (dead until pull2 writes): ranks[E] u32, then the three
    // record streams ssst/es/et (u64[E] each), 16B-aligned. Total ~28E bytes.
    unsigned* ranks = (unsigned*)d_out;
    char* po = (char*)d_out + (((size_t)E * 4 + 15) & ~(size_t)15);
    u64* ssst = (u64*)po;
    u64* es   = ssst + (size_t)E;
    u64* et   = es + (size_t)E;
    float* out = (float*)d_out;

    hipMemsetAsync(cnt32, 0, (size_t)total * sizeof(unsigned), stream);

    long long nd = (long long)N * D;
    int blkC = (int)((nd / 2 + 255) / 256);
    int blkE = (E + 255) / 256;
    int nEB  = (E + EPT * 256 - 1) / (EPT * 256);
    cnt_tobf_kernel<<<nEB + blkC, 256, 0, stream>>>(row, col, ew, cnt32, ranks,
                                                    x_s, x_t, xb_s, xb_t,
                                                    E, N, nEB, nd);
    scanAI_kernel<<<nTiles, 256, 0, stream>>>(cnt32, dinv, tsum, total);
    scanC_kernel<<<nTiles, 256, 0, stream>>>(cnt32, tsum, start, total, 2 * E);

    int blkS = (E / 4 + 256) / 256 + 1;
    slot_kernel<<<blkS, 256, 0, stream>>>(start, row, col, ew, ranks, dinv,
                                          ssst, es, et, E, N);

    // slot-range size per XCD, multiple of 8 slots (64B lines of int2)
    int SL = ((2 * E + NXCD - 1) / NXCD + 7) & ~7;
    fillX_kernel<<<NXCD * blkE, 256, 0, stream>>>(ssst, es, et, edges, E, SL);

    long long pull_threads = (long long)total * 64;
    int blkP = (int)((pull_threads + 255) / 256);
    pull1_kernel<<<blkP, 256, 0, stream>>>(start, (const int2*)edges, dinv, xb_s, xb_t,
                                           x_s, x_t, ab_s, ab_t, N);
    pull2_kernel<<<blkP, 256, 0, stream>>>(start, (const int2*)edges, dinv, ab_s, ab_t,
                                           x_s, x_t, out, w_s, w_t, N);
}